// Round 1
// baseline (640.023 us; speedup 1.0000x reference)
//
#include <hip/hip_runtime.h>
#include <math.h>

// Shapes (hardcoded from reference)
// B=2, LS=2048, G=32, KNN=16, DIM=256, PE=32, H=8, DH=32, INNER=256, FF=1024
#define LS 2048
#define NG 32
#define ROWS_B 2080      // LS+G
#define DIM 256
#define PE 32
#define NH 8
#define DH 32
#define FFD 1024
#define NCTX 49          // 1 + KNN + G
#define SCALE 0.17677669529663687f  // 1/sqrt(32)

// ---------------- LayerNorm over 256-wide rows ----------------
__global__ __launch_bounds__(256) void ln_rows_k(
    const float* __restrict__ in, const float* __restrict__ gam,
    const float* __restrict__ bet, float* __restrict__ out,
    int irpb, int ibsr, int ioff, int orpb, int obsr, int ooff)
{
    __shared__ float red[8];
    int r = blockIdx.x, t = threadIdx.x;
    size_t ip = ((size_t)(r / irpb) * ibsr + ioff + (r % irpb)) * DIM + t;
    size_t op = ((size_t)(r / orpb) * obsr + ooff + (r % orpb)) * DIM + t;
    float v = in[ip];
    float a = v, b2 = v * v;
    #pragma unroll
    for (int m = 32; m >= 1; m >>= 1) {
        a  += __shfl_xor(a, m);
        b2 += __shfl_xor(b2, m);
    }
    if ((t & 63) == 0) { red[t >> 6] = a; red[4 + (t >> 6)] = b2; }
    __syncthreads();
    float mean = (red[0] + red[1] + red[2] + red[3]) * (1.0f / 256.0f);
    float var  = (red[4] + red[5] + red[6] + red[7]) * (1.0f / 256.0f) - mean * mean;
    out[op] = (v - mean) * rsqrtf(var + 1e-5f) * gam[t] + bet[t];
}

// ---------------- GELU (tanh approx, matches jax.nn.gelu default) ----------------
__device__ __forceinline__ float gelu_f(float x)
{
    float x3 = x * x * x;
    return 0.5f * x * (1.0f + tanhf(0.7978845608028654f * (x + 0.044715f * x3)));
}

// ---------------- f32 tiled GEMM: C[map] = (RES? Res[map]:0) + act(A[map]@B + bias) ----
// 64x64 tile, BK=16, 256 threads, 4x4 per thread. Row mappings allow reading/writing
// batch-strided sub-blocks (latents/d_out layout (B, LS+G, 256)).
template<int BIAS, int DOGELU, int RES>
__global__ __launch_bounds__(256) void gemm_k(
    const float* __restrict__ A, const float* __restrict__ Bm,
    const float* __restrict__ bias, const float* __restrict__ Res,
    float* __restrict__ C, int M, int N, int K,
    int arpb, int absr, int aoff, int crpb, int cbsr, int coff)
{
    __shared__ float As[64][20];
    __shared__ float Bs[16][64];
    int t = threadIdx.x;
    int col0 = blockIdx.x * 64, row0 = blockIdx.y * 64;
    int tx = t & 15, ty = t >> 4;
    int la_r = t >> 2, la_c = (t & 3) << 2;
    int ar = row0 + la_r;
    size_t a_base = ((size_t)(ar / arpb) * absr + aoff + (ar % arpb)) * (size_t)K;
    float acc[4][4] = {};
    for (int kk = 0; kk < K; kk += 16) {
        float4 av = *(const float4*)(A + a_base + kk + la_c);
        float4 bv = *(const float4*)(Bm + (size_t)(kk + ty) * N + col0 + (tx << 2));
        *(float4*)&As[la_r][la_c] = av;
        *(float4*)&Bs[ty][tx << 2] = bv;
        __syncthreads();
        #pragma unroll
        for (int k = 0; k < 16; ++k) {
            float4 b = *(float4*)&Bs[k][tx << 2];
            float a0 = As[(ty << 2) + 0][k];
            float a1 = As[(ty << 2) + 1][k];
            float a2 = As[(ty << 2) + 2][k];
            float a3 = As[(ty << 2) + 3][k];
            acc[0][0] += a0 * b.x; acc[0][1] += a0 * b.y; acc[0][2] += a0 * b.z; acc[0][3] += a0 * b.w;
            acc[1][0] += a1 * b.x; acc[1][1] += a1 * b.y; acc[1][2] += a1 * b.z; acc[1][3] += a1 * b.w;
            acc[2][0] += a2 * b.x; acc[2][1] += a2 * b.y; acc[2][2] += a2 * b.z; acc[2][3] += a2 * b.w;
            acc[3][0] += a3 * b.x; acc[3][1] += a3 * b.y; acc[3][2] += a3 * b.z; acc[3][3] += a3 * b.w;
        }
        __syncthreads();
    }
    #pragma unroll
    for (int i = 0; i < 4; ++i) {
        int r = row0 + (ty << 2) + i;
        size_t cp = ((size_t)(r / crpb) * cbsr + coff + (r % crpb)) * (size_t)N + col0 + (tx << 2);
        #pragma unroll
        for (int j = 0; j < 4; ++j) {
            float o = acc[i][j];
            if (BIAS)   o += bias[col0 + (tx << 2) + j];
            if (DOGELU) o = gelu_f(o);
            if (RES)    o += Res[cp + j];
            C[cp + j] = o;
        }
    }
}

// ---------------- fused spatial attention ----------------
// One block per (b,l). K/V for the 17 local contexts are reconstructed as
// gathered (x@Wx) + rpe@Wpe (Wpe columns held in registers); 32 glob contexts
// are precomputed (l-independent). V staged in LDS; softmax over 49 with
// gaussian-distance bias; weighted sum.
__global__ __launch_bounds__(256) void attn_sp_k(
    const float* __restrict__ Q, const float* __restrict__ XK,
    const float* __restrict__ XV, const float* __restrict__ KGL,
    const float* __restrict__ VGL, const int* __restrict__ idx,
    const float* __restrict__ rpe, const float* __restrict__ srpe,
    const float* __restrict__ dist, const float* __restrict__ wkpe,
    const float* __restrict__ wvpe, const float* __restrict__ lsig,
    const float* __restrict__ gbias, float* __restrict__ O)
{
    __shared__ float s_v[NCTX * 256];
    __shared__ float s_rpe[17 * 32];
    __shared__ float s_sc[NCTX * 8];
    __shared__ int   s_idx[16];
    int t = threadIdx.x;
    int r = blockIdx.x;          // b*LS + l
    int h = t >> 5, d = t & 31;
    int b = r >> 11;             // / LS
    size_t rbase = (size_t)r * 256;

    if (t < 32) s_rpe[t] = srpe[(size_t)r * 32 + t];
    for (int i = t; i < 512; i += 256) s_rpe[32 + i] = rpe[(size_t)r * 512 + i];
    if (t < 16) s_idx[t] = idx[r * 16 + t];
    float wk[32], wv[32];
    #pragma unroll
    for (int p = 0; p < 32; ++p) {
        wk[p] = wkpe[p * 256 + t];
        wv[p] = wvpe[p * 256 + t];
    }
    float qt = Q[rbase + t];
    __syncthreads();

    for (int c = 0; c < 17; ++c) {
        int row = (c == 0) ? r : ((b << 11) + s_idx[c - 1]);
        size_t rb = (size_t)row * 256 + t;
        float kt = XK[rb], vt = XV[rb];
        const float* rv = &s_rpe[c * 32];
        #pragma unroll
        for (int p = 0; p < 32; ++p) {
            kt += rv[p] * wk[p];
            vt += rv[p] * wv[p];
        }
        s_v[c * 256 + t] = vt;
        float ps = qt * kt;
        ps += __shfl_xor(ps, 16); ps += __shfl_xor(ps, 8); ps += __shfl_xor(ps, 4);
        ps += __shfl_xor(ps, 2);  ps += __shfl_xor(ps, 1);
        if (d == 0) s_sc[c * 8 + h] = ps * SCALE;
    }
    for (int c = 17; c < NCTX; ++c) {
        size_t gb = ((size_t)(b * NG + (c - 17))) * 256 + t;
        float kt = KGL[gb];
        s_v[c * 256 + t] = VGL[gb];
        float ps = qt * kt;
        ps += __shfl_xor(ps, 16); ps += __shfl_xor(ps, 8); ps += __shfl_xor(ps, 4);
        ps += __shfl_xor(ps, 2);  ps += __shfl_xor(ps, 1);
        if (d == 0) s_sc[c * 8 + h] = ps * SCALE;
    }
    __syncthreads();
    if (t < 8) {
        float ssq = expf(2.0f * lsig[t]);
        float inv2s = 1.0f / (2.0f * ssq);
        float gb = gbias[0];
        float mx = -1e30f;
        for (int c = 0; c < NCTX; ++c) {
            float bia;
            if (c == 0) bia = 0.0f;
            else if (c < 17) {
                float dd = dist[(size_t)r * 16 + (c - 1)];
                bia = -dd * dd * inv2s;
            } else bia = gb;
            float lg = s_sc[c * 8 + t] + bia;
            s_sc[c * 8 + t] = lg;
            mx = fmaxf(mx, lg);
        }
        float sum = 0.0f;
        for (int c = 0; c < NCTX; ++c) {
            float e = expf(s_sc[c * 8 + t] - mx);
            s_sc[c * 8 + t] = e;
            sum += e;
        }
        float inv = 1.0f / sum;
        for (int c = 0; c < NCTX; ++c) s_sc[c * 8 + t] *= inv;
    }
    __syncthreads();
    float acc = 0.0f;
    for (int c = 0; c < NCTX; ++c) acc += s_sc[c * 8 + h] * s_v[c * 256 + t];
    O[rbase + t] = acc;
}

// ---------------- global attention: scores ----------------
__global__ __launch_bounds__(256) void ga_scores_k(
    const float* __restrict__ QG, const float* __restrict__ KG, float* __restrict__ A2)
{
    int t = threadIdx.x;
    int blk = blockIdx.x;           // b*2080 + c
    int b = blk / ROWS_B, c = blk % ROWS_B;
    int h = t >> 5, d = t & 31;
    float kt = KG[(size_t)blk * 256 + t];
    for (int g = 0; g < NG; ++g) {
        float ps = QG[((size_t)(b * NG + g)) * 256 + t] * kt;
        ps += __shfl_xor(ps, 16); ps += __shfl_xor(ps, 8); ps += __shfl_xor(ps, 4);
        ps += __shfl_xor(ps, 2);  ps += __shfl_xor(ps, 1);
        if (d == 0) A2[((size_t)(b * NH + h) * NG + g) * ROWS_B + c] = ps * SCALE;
        // note: + ga_gbias omitted — constant shift is a softmax no-op
    }
}

// ---------------- global attention: row softmax over 2080 ----------------
__global__ __launch_bounds__(256) void ga_softmax_k(float* __restrict__ A2)
{
    __shared__ float red[8];
    int t = threadIdx.x;
    float* row = A2 + (size_t)blockIdx.x * ROWS_B;
    float lm = -1e30f;
    for (int i = t; i < ROWS_B; i += 256) lm = fmaxf(lm, row[i]);
    #pragma unroll
    for (int m = 32; m >= 1; m >>= 1) lm = fmaxf(lm, __shfl_xor(lm, m));
    if ((t & 63) == 0) red[t >> 6] = lm;
    __syncthreads();
    float M = fmaxf(fmaxf(red[0], red[1]), fmaxf(red[2], red[3]));
    float ls = 0.0f;
    for (int i = t; i < ROWS_B; i += 256) {
        float e = expf(row[i] - M);
        row[i] = e;
        ls += e;
    }
    #pragma unroll
    for (int m = 32; m >= 1; m >>= 1) ls += __shfl_xor(ls, m);
    if ((t & 63) == 0) red[4 + (t >> 6)] = ls;
    __syncthreads();
    float inv = 1.0f / (red[4] + red[5] + red[6] + red[7]);
    for (int i = t; i < ROWS_B; i += 256) row[i] *= inv;
}

// ---------------- global attention: weighted V (split-K over keys) ----------------
__global__ __launch_bounds__(256) void ga_wv_k(
    const float* __restrict__ A2, const float* __restrict__ VG, float* __restrict__ OGP)
{
    int t = threadIdx.x;
    int bg = blockIdx.x;       // b*32+g
    int s = blockIdx.y;        // 0..7
    int b = bg >> 5, g = bg & 31;
    int h = t >> 5;
    const float* w = A2 + ((size_t)(b * NH + h) * NG + g) * ROWS_B;
    const float* v = VG + (size_t)b * ROWS_B * 256;
    float acc = 0.0f;
    int c0 = s * 260, c1 = c0 + 260;
    for (int c = c0; c < c1; ++c) acc += w[c] * v[(size_t)c * 256 + t];
    OGP[((size_t)bg * 8 + s) * 256 + t] = acc;
}

__global__ __launch_bounds__(256) void ga_red_k(
    const float* __restrict__ OGP, float* __restrict__ OG)
{
    int t = threadIdx.x, bg = blockIdx.x;
    float a = 0.0f;
    #pragma unroll
    for (int s = 0; s < 8; ++s) a += OGP[((size_t)bg * 8 + s) * 256 + t];
    OG[(size_t)bg * 256 + t] = a;
}

// ---------------- launch ----------------
extern "C" void kernel_launch(void* const* d_in, const int* in_sizes, int n_in,
                              void* d_out, int out_size, void* d_ws, size_t ws_size,
                              hipStream_t stream)
{
    const float* latents = (const float*)d_in[0];
    const int*   idx     = (const int*)d_in[1];
    const float* rpe     = (const float*)d_in[2];
    const float* srpe    = (const float*)d_in[3];
    const float* dist    = (const float*)d_in[4];
    const float* sa_wq   = (const float*)d_in[6];
    const float* sa_wk   = (const float*)d_in[7];
    const float* sa_wv   = (const float*)d_in[8];
    const float* sa_wo   = (const float*)d_in[9];
    const float* sa_bo   = (const float*)d_in[10];
    const float* lsig    = (const float*)d_in[11];
    const float* gbias   = (const float*)d_in[12];
    const float* ln1g    = (const float*)d_in[13];
    const float* ln1b    = (const float*)d_in[14];
    const float* ln2g    = (const float*)d_in[15];
    const float* ln2b    = (const float*)d_in[16];
    const float* sff_w1  = (const float*)d_in[17];
    const float* sff_b1  = (const float*)d_in[18];
    const float* sff_w2  = (const float*)d_in[19];
    const float* sff_b2  = (const float*)d_in[20];
    const float* ga_wq   = (const float*)d_in[21];
    const float* ga_wk   = (const float*)d_in[22];
    const float* ga_wv   = (const float*)d_in[23];
    const float* ga_wo   = (const float*)d_in[24];
    const float* ga_bo   = (const float*)d_in[25];
    const float* ln3g    = (const float*)d_in[27];
    const float* ln3b    = (const float*)d_in[28];
    const float* ln4g    = (const float*)d_in[29];
    const float* ln4b    = (const float*)d_in[30];
    const float* gff_w1  = (const float*)d_in[31];
    const float* gff_b1  = (const float*)d_in[32];
    const float* gff_w2  = (const float*)d_in[33];
    const float* gff_b2  = (const float*)d_in[34];
    float* out = (float*)d_out;

    const size_t SZ   = (size_t)4096 * 256;   // 1,048,576
    const size_t KGSZ = (size_t)2 * ROWS_B * 256; // 1,064,960
    float* ws  = (float*)d_ws;
    float* X   = ws;                 // [0, SZ)           LN1 out, later LN2 out
    float* Qb  = ws + SZ;            // [SZ, 2SZ)
    float* XK  = ws + 2 * SZ;
    float* XV  = ws + 3 * SZ;
    float* O   = ws + 4 * SZ;
    float* H1  = ws + SZ;            // overlays Qb..O after attention (4SZ floats)
    float* KG  = ws + SZ;            // overlays H1 after ff2
    float* VG  = KG + KGSZ;
    float* KGL = ws + 5 * SZ;
    float* VGL = KGL + 16384;
    float* GQ  = VGL + 16384;
    float* QG  = GQ + 16384;
    float* OG  = QG + 16384;
    float* GLN = OG + 16384;
    float* GH  = GLN + 16384;
    float* A2  = GH + 65536;
    float* OGP = A2 + KGSZ;

    dim3 blk(256);
    // wk_pe / wv_pe = rows 256..287 of the 288x256 K/V weights
    const float* wkpe = sa_wk + 256 * 256;
    const float* wvpe = sa_wv + 256 * 256;

    // LN1 (spatial) and LN3 (glob)
    ln_rows_k<<<dim3(4096), blk, 0, stream>>>(latents, ln1g, ln1b, X, LS, ROWS_B, 0, LS, LS, 0);
    ln_rows_k<<<dim3(64),   blk, 0, stream>>>(latents, ln3g, ln3b, GQ, NG, ROWS_B, LS, NG, NG, 0);

    // projections: q, x@wk_x, x@wv_x ; glob (raw) @ wk_x / wv_x
    gemm_k<0,0,0><<<dim3(4,64), blk, 0, stream>>>(X, sa_wq, nullptr, nullptr, Qb, 4096,256,256, 4096,4096,0, 4096,4096,0);
    gemm_k<0,0,0><<<dim3(4,64), blk, 0, stream>>>(X, sa_wk, nullptr, nullptr, XK, 4096,256,256, 4096,4096,0, 4096,4096,0);
    gemm_k<0,0,0><<<dim3(4,64), blk, 0, stream>>>(X, sa_wv, nullptr, nullptr, XV, 4096,256,256, 4096,4096,0, 4096,4096,0);
    gemm_k<0,0,0><<<dim3(4,1),  blk, 0, stream>>>(latents, sa_wk, nullptr, nullptr, KGL, 64,256,256, NG,ROWS_B,LS, 64,64,0);
    gemm_k<0,0,0><<<dim3(4,1),  blk, 0, stream>>>(latents, sa_wv, nullptr, nullptr, VGL, 64,256,256, NG,ROWS_B,LS, 64,64,0);

    // fused spatial attention -> O
    attn_sp_k<<<dim3(4096), blk, 0, stream>>>(Qb, XK, XV, KGL, VGL, idx, rpe, srpe, dist,
                                              wkpe, wvpe, lsig, gbias, O);

    // spatial residual: d_out[:, :LS] = latents + O@wo + bo
    gemm_k<1,0,1><<<dim3(4,64), blk, 0, stream>>>(O, sa_wo, sa_bo, latents, out, 4096,256,256, 4096,4096,0, LS,ROWS_B,0);

    // spatial FF
    ln_rows_k<<<dim3(4096), blk, 0, stream>>>(out, ln2g, ln2b, X, LS, ROWS_B, 0, LS, LS, 0);
    gemm_k<1,1,0><<<dim3(16,64), blk, 0, stream>>>(X, sff_w1, sff_b1, nullptr, H1, 4096,1024,256, 4096,4096,0, 4096,4096,0);
    gemm_k<1,0,1><<<dim3(4,64),  blk, 0, stream>>>(H1, sff_w2, sff_b2, out, out, 4096,256,1024, 4096,4096,0, LS,ROWS_B,0);

    // global attention projections (kv = [spatial_new ; gq_in])
    gemm_k<0,0,0><<<dim3(4,64), blk, 0, stream>>>(out, ga_wk, nullptr, nullptr, KG, 4096,256,256, LS,ROWS_B,0, LS,ROWS_B,0);
    gemm_k<0,0,0><<<dim3(4,1),  blk, 0, stream>>>(GQ,  ga_wk, nullptr, nullptr, KG, 64,256,256, 64,64,0, NG,ROWS_B,LS);
    gemm_k<0,0,0><<<dim3(4,64), blk, 0, stream>>>(out, ga_wv, nullptr, nullptr, VG, 4096,256,256, LS,ROWS_B,0, LS,ROWS_B,0);
    gemm_k<0,0,0><<<dim3(4,1),  blk, 0, stream>>>(GQ,  ga_wv, nullptr, nullptr, VG, 64,256,256, 64,64,0, NG,ROWS_B,LS);
    gemm_k<0,0,0><<<dim3(4,1),  blk, 0, stream>>>(GQ,  ga_wq, nullptr, nullptr, QG, 64,256,256, 64,64,0, 64,64,0);

    ga_scores_k<<<dim3(2 * ROWS_B), blk, 0, stream>>>(QG, KG, A2);
    ga_softmax_k<<<dim3(512), blk, 0, stream>>>(A2);
    ga_wv_k<<<dim3(64, 8), blk, 0, stream>>>(A2, VG, OGP);
    ga_red_k<<<dim3(64), blk, 0, stream>>>(OGP, OG);

    // glob residual: d_out[:, LS:] = latents_glob + OG@wo + bo
    gemm_k<1,0,1><<<dim3(4,1), blk, 0, stream>>>(OG, ga_wo, ga_bo, latents, out, 64,256,256, 64,64,0, NG,ROWS_B,LS);

    // glob FF
    ln_rows_k<<<dim3(64), blk, 0, stream>>>(out, ln4g, ln4b, GLN, NG, ROWS_B, LS, NG, NG, 0);
    gemm_k<1,1,0><<<dim3(16,1), blk, 0, stream>>>(GLN, gff_w1, gff_b1, nullptr, GH, 64,1024,256, 64,64,0, 64,64,0);
    gemm_k<1,0,1><<<dim3(4,1),  blk, 0, stream>>>(GH, gff_w2, gff_b2, out, out, 64,256,1024, 64,64,0, NG,ROWS_B,LS);
}

// Round 2
// 513.694 us; speedup vs baseline: 1.2459x; 1.2459x over previous
//
#include <hip/hip_runtime.h>
#include <math.h>

// Shapes (hardcoded from reference)
// B=2, LS=2048, G=32, KNN=16, DIM=256, PE=32, H=8, DH=32, INNER=256, FF=1024
#define LS 2048
#define NG 32
#define ROWS_B 2080      // LS+G
#define DIM 256
#define PE 32
#define NH 8
#define DH 32
#define FFD 1024
#define NCTX 49          // 1 + KNN + G
#define SCALE 0.17677669529663687f  // 1/sqrt(32)

// ---------------- LayerNorm over 256-wide rows ----------------
__global__ __launch_bounds__(256) void ln_rows_k(
    const float* __restrict__ in, const float* __restrict__ gam,
    const float* __restrict__ bet, float* __restrict__ out,
    int irpb, int ibsr, int ioff, int orpb, int obsr, int ooff)
{
    __shared__ float red[8];
    int r = blockIdx.x, t = threadIdx.x;
    size_t ip = ((size_t)(r / irpb) * ibsr + ioff + (r % irpb)) * DIM + t;
    size_t op = ((size_t)(r / orpb) * obsr + ooff + (r % orpb)) * DIM + t;
    float v = in[ip];
    float a = v, b2 = v * v;
    #pragma unroll
    for (int m = 32; m >= 1; m >>= 1) {
        a  += __shfl_xor(a, m);
        b2 += __shfl_xor(b2, m);
    }
    if ((t & 63) == 0) { red[t >> 6] = a; red[4 + (t >> 6)] = b2; }
    __syncthreads();
    float mean = (red[0] + red[1] + red[2] + red[3]) * (1.0f / 256.0f);
    float var  = (red[4] + red[5] + red[6] + red[7]) * (1.0f / 256.0f) - mean * mean;
    out[op] = (v - mean) * rsqrtf(var + 1e-5f) * gam[t] + bet[t];
}

// ---------------- GELU (tanh approx, matches jax.nn.gelu default) ----------------
__device__ __forceinline__ float gelu_f(float x)
{
    float x3 = x * x * x;
    return 0.5f * x * (1.0f + tanhf(0.7978845608028654f * (x + 0.044715f * x3)));
}

// ---------------- f32 tiled GEMM: C[map] = (RES? Res[map]:0) + act(A[map]@B + bias) ----
// 64x64 tile, BK=16, 256 threads, 4x4 per thread. As stored K-major (transposed)
// so the inner loop is two ds_read_b128. Row mappings allow batch-strided views.
template<int BIAS, int DOGELU, int RES>
__global__ __launch_bounds__(256) void gemm_k(
    const float* __restrict__ A, const float* __restrict__ Bm,
    const float* __restrict__ bias, const float* __restrict__ Res,
    float* __restrict__ C, int M, int N, int K,
    int arpb, int absr, int aoff, int crpb, int cbsr, int coff)
{
    __shared__ float As[16][68];   // [k][row], padded: 2-way max on store, free
    __shared__ float Bs[16][64];
    int t = threadIdx.x;
    int col0 = blockIdx.x * 64, row0 = blockIdx.y * 64;
    int tx = t & 15, ty = t >> 4;
    int la_r = t >> 2, la_c = (t & 3) << 2;
    int ar = row0 + la_r;
    size_t a_base = ((size_t)(ar / arpb) * absr + aoff + (ar % arpb)) * (size_t)K;
    float acc[4][4] = {};
    for (int kk = 0; kk < K; kk += 16) {
        float4 av = *(const float4*)(A + a_base + kk + la_c);
        float4 bv = *(const float4*)(Bm + (size_t)(kk + ty) * N + col0 + (tx << 2));
        As[la_c + 0][la_r] = av.x;
        As[la_c + 1][la_r] = av.y;
        As[la_c + 2][la_r] = av.z;
        As[la_c + 3][la_r] = av.w;
        *(float4*)&Bs[ty][tx << 2] = bv;
        __syncthreads();
        #pragma unroll
        for (int k = 0; k < 16; ++k) {
            float4 a = *(float4*)&As[k][ty << 2];
            float4 b = *(float4*)&Bs[k][tx << 2];
            acc[0][0] += a.x * b.x; acc[0][1] += a.x * b.y; acc[0][2] += a.x * b.z; acc[0][3] += a.x * b.w;
            acc[1][0] += a.y * b.x; acc[1][1] += a.y * b.y; acc[1][2] += a.y * b.z; acc[1][3] += a.y * b.w;
            acc[2][0] += a.z * b.x; acc[2][1] += a.z * b.y; acc[2][2] += a.z * b.z; acc[2][3] += a.z * b.w;
            acc[3][0] += a.w * b.x; acc[3][1] += a.w * b.y; acc[3][2] += a.w * b.z; acc[3][3] += a.w * b.w;
        }
        __syncthreads();
    }
    #pragma unroll
    for (int i = 0; i < 4; ++i) {
        int r = row0 + (ty << 2) + i;
        size_t cp = ((size_t)(r / crpb) * cbsr + coff + (r % crpb)) * (size_t)N + col0 + (tx << 2);
        #pragma unroll
        for (int j = 0; j < 4; ++j) {
            float o = acc[i][j];
            if (BIAS)   o += bias[col0 + (tx << 2) + j];
            if (DOGELU) o = gelu_f(o);
            if (RES)    o += Res[cp + j];
            C[cp + j] = o;
        }
    }
}

// ---------------- fused spatial attention, online softmax ----------------
// One block per (b,l), thread t = (h= t>>5, d = t&31). Single pass over the
// 49 contexts with flash-style m/l/acc rescaling. Key algebra:
//   score_c = q . Kx[row_c]  +  rpe_c . qw[:,h]     (qw = per-head q @ Wkpe^T)
//   out     = sum_c p_c Vx[row_c]  +  (sum_c p_c rpe_c) @ Wvpe
// so NO per-context 32-FMA projections; qw is a one-time 32-step butterfly,
// the rpe-V projection is a one-time 32-step epilogue (lane d holds r_acc[p=d]).
__global__ __launch_bounds__(256) void attn_sp_k(
    const float* __restrict__ Q, const float* __restrict__ XK,
    const float* __restrict__ XV, const float* __restrict__ KGL,
    const float* __restrict__ VGL, const int* __restrict__ idx,
    const float* __restrict__ rpe, const float* __restrict__ srpe,
    const float* __restrict__ dist, const float* __restrict__ wkpe,
    const float* __restrict__ wvpe, const float* __restrict__ lsig,
    const float* __restrict__ gbias, float* __restrict__ O)
{
    __shared__ float s_rpe[17 * 32];
    __shared__ int   s_idx[16];
    int t = threadIdx.x;
    int r = blockIdx.x;          // b*LS + l
    int h = t >> 5, d = t & 31;
    int b = r >> 11;
    size_t rbase = (size_t)r * 256;

    if (t < 32) s_rpe[t] = srpe[(size_t)r * 32 + t];
    for (int i = t; i < 512; i += 256) s_rpe[32 + i] = rpe[(size_t)r * 512 + i];
    if (t < 16) s_idx[t] = idx[r * 16 + t];

    float qt = Q[rbase + t];
    float inv2s = 1.0f / (2.0f * __expf(2.0f * lsig[h]));
    float gb = gbias[0];

    // qw[p=d, h] = sum_{d' in head h} q_d' * Wkpe[p][h*32+d']
    float qw = 0.0f;
    #pragma unroll
    for (int p = 0; p < 32; ++p) {
        float part = qt * wkpe[p * 256 + t];
        part += __shfl_xor(part, 16); part += __shfl_xor(part, 8);
        part += __shfl_xor(part, 4);  part += __shfl_xor(part, 2);
        part += __shfl_xor(part, 1);
        if (d == p) qw = part;
    }
    __syncthreads();

    float m = -3.0e38f, l = 0.0f, acc = 0.0f, r_acc = 0.0f;

    // 17 local contexts (self + 16 neighbors)
    for (int c = 0; c < 17; ++c) {
        int row = (c == 0) ? r : ((b << 11) + s_idx[c - 1]);
        size_t rb = (size_t)row * 256 + t;
        float kt = XK[rb];
        float vt = XV[rb];
        float rv = s_rpe[c * 32 + d];
        float part = qt * kt + rv * qw;
        part += __shfl_xor(part, 16); part += __shfl_xor(part, 8);
        part += __shfl_xor(part, 4);  part += __shfl_xor(part, 2);
        part += __shfl_xor(part, 1);
        float bia = 0.0f;
        if (c > 0) {
            float dd = dist[(size_t)r * 16 + (c - 1)];
            bia = -dd * dd * inv2s;
        }
        float s = part * SCALE + bia;
        float m_new = fmaxf(m, s);
        float corr = __expf(m - m_new);
        float p = __expf(s - m_new);
        l = l * corr + p;
        acc = acc * corr + p * vt;
        r_acc = r_acc * corr + p * rv;
        m = m_new;
    }
    // 32 global contexts (rpe part is zero)
    for (int c = 0; c < NG; ++c) {
        size_t gb2 = ((size_t)(b * NG + c)) * 256 + t;
        float kt = KGL[gb2];
        float vt = VGL[gb2];
        float part = qt * kt;
        part += __shfl_xor(part, 16); part += __shfl_xor(part, 8);
        part += __shfl_xor(part, 4);  part += __shfl_xor(part, 2);
        part += __shfl_xor(part, 1);
        float s = part * SCALE + gb;
        float m_new = fmaxf(m, s);
        float corr = __expf(m - m_new);
        float p = __expf(s - m_new);
        l = l * corr + p;
        acc = acc * corr + p * vt;
        m = m_new;
    }

    // epilogue: add (r_acc @ Wvpe) and normalize
    float vo = acc;
    #pragma unroll
    for (int p = 0; p < 32; ++p) {
        float rp = __shfl(r_acc, p, 32);
        vo += rp * wvpe[p * 256 + t];
    }
    O[rbase + t] = vo / l;
}

// ---------------- global attention: scores ----------------
__global__ __launch_bounds__(256) void ga_scores_k(
    const float* __restrict__ QG, const float* __restrict__ KG, float* __restrict__ A2)
{
    int t = threadIdx.x;
    int blk = blockIdx.x;           // b*2080 + c
    int b = blk / ROWS_B, c = blk % ROWS_B;
    int h = t >> 5, d = t & 31;
    float kt = KG[(size_t)blk * 256 + t];
    for (int g = 0; g < NG; ++g) {
        float ps = QG[((size_t)(b * NG + g)) * 256 + t] * kt;
        ps += __shfl_xor(ps, 16); ps += __shfl_xor(ps, 8); ps += __shfl_xor(ps, 4);
        ps += __shfl_xor(ps, 2);  ps += __shfl_xor(ps, 1);
        if (d == 0) A2[((size_t)(b * NH + h) * NG + g) * ROWS_B + c] = ps * SCALE;
        // + ga_gbias omitted — constant shift is a softmax no-op
    }
}

// ---------------- global attention: row softmax over 2080 ----------------
__global__ __launch_bounds__(256) void ga_softmax_k(float* __restrict__ A2)
{
    __shared__ float red[8];
    int t = threadIdx.x;
    float* row = A2 + (size_t)blockIdx.x * ROWS_B;
    float lm = -1e30f;
    for (int i = t; i < ROWS_B; i += 256) lm = fmaxf(lm, row[i]);
    #pragma unroll
    for (int m = 32; m >= 1; m >>= 1) lm = fmaxf(lm, __shfl_xor(lm, m));
    if ((t & 63) == 0) red[t >> 6] = lm;
    __syncthreads();
    float M = fmaxf(fmaxf(red[0], red[1]), fmaxf(red[2], red[3]));
    float ls = 0.0f;
    for (int i = t; i < ROWS_B; i += 256) {
        float e = __expf(row[i] - M);
        row[i] = e;
        ls += e;
    }
    #pragma unroll
    for (int m = 32; m >= 1; m >>= 1) ls += __shfl_xor(ls, m);
    if ((t & 63) == 0) red[4 + (t >> 6)] = ls;
    __syncthreads();
    float inv = 1.0f / (red[4] + red[5] + red[6] + red[7]);
    for (int i = t; i < ROWS_B; i += 256) row[i] *= inv;
}

// ---------------- global attention: weighted V (split-K over keys) ----------------
__global__ __launch_bounds__(256) void ga_wv_k(
    const float* __restrict__ A2, const float* __restrict__ VG, float* __restrict__ OGP)
{
    int t = threadIdx.x;
    int bg = blockIdx.x;       // b*32+g
    int s = blockIdx.y;        // 0..7
    int b = bg >> 5, g = bg & 31;
    int h = t >> 5;
    const float* w = A2 + ((size_t)(b * NH + h) * NG + g) * ROWS_B;
    const float* v = VG + (size_t)b * ROWS_B * 256;
    float acc = 0.0f;
    int c0 = s * 260, c1 = c0 + 260;
    for (int c = c0; c < c1; ++c) acc += w[c] * v[(size_t)c * 256 + t];
    OGP[((size_t)bg * 8 + s) * 256 + t] = acc;
}

__global__ __launch_bounds__(256) void ga_red_k(
    const float* __restrict__ OGP, float* __restrict__ OG)
{
    int t = threadIdx.x, bg = blockIdx.x;
    float a = 0.0f;
    #pragma unroll
    for (int s = 0; s < 8; ++s) a += OGP[((size_t)bg * 8 + s) * 256 + t];
    OG[(size_t)bg * 256 + t] = a;
}

// ---------------- launch ----------------
extern "C" void kernel_launch(void* const* d_in, const int* in_sizes, int n_in,
                              void* d_out, int out_size, void* d_ws, size_t ws_size,
                              hipStream_t stream)
{
    const float* latents = (const float*)d_in[0];
    const int*   idx     = (const int*)d_in[1];
    const float* rpe     = (const float*)d_in[2];
    const float* srpe    = (const float*)d_in[3];
    const float* dist    = (const float*)d_in[4];
    const float* sa_wq   = (const float*)d_in[6];
    const float* sa_wk   = (const float*)d_in[7];
    const float* sa_wv   = (const float*)d_in[8];
    const float* sa_wo   = (const float*)d_in[9];
    const float* sa_bo   = (const float*)d_in[10];
    const float* lsig    = (const float*)d_in[11];
    const float* gbias   = (const float*)d_in[12];
    const float* ln1g    = (const float*)d_in[13];
    const float* ln1b    = (const float*)d_in[14];
    const float* ln2g    = (const float*)d_in[15];
    const float* ln2b    = (const float*)d_in[16];
    const float* sff_w1  = (const float*)d_in[17];
    const float* sff_b1  = (const float*)d_in[18];
    const float* sff_w2  = (const float*)d_in[19];
    const float* sff_b2  = (const float*)d_in[20];
    const float* ga_wq   = (const float*)d_in[21];
    const float* ga_wk   = (const float*)d_in[22];
    const float* ga_wv   = (const float*)d_in[23];
    const float* ga_wo   = (const float*)d_in[24];
    const float* ga_bo   = (const float*)d_in[25];
    const float* ln3g    = (const float*)d_in[27];
    const float* ln3b    = (const float*)d_in[28];
    const float* ln4g    = (const float*)d_in[29];
    const float* ln4b    = (const float*)d_in[30];
    const float* gff_w1  = (const float*)d_in[31];
    const float* gff_b1  = (const float*)d_in[32];
    const float* gff_w2  = (const float*)d_in[33];
    const float* gff_b2  = (const float*)d_in[34];
    float* out = (float*)d_out;

    const size_t SZ   = (size_t)4096 * 256;   // 1,048,576
    const size_t KGSZ = (size_t)2 * ROWS_B * 256; // 1,064,960
    float* ws  = (float*)d_ws;
    float* X   = ws;                 // LN1 out, later LN2 out
    float* Qb  = ws + SZ;
    float* XK  = ws + 2 * SZ;
    float* XV  = ws + 3 * SZ;
    float* O   = ws + 4 * SZ;
    float* H1  = ws + SZ;            // overlays Qb..O after attention
    float* KG  = ws + SZ;            // overlays H1 after ff2
    float* VG  = KG + KGSZ;
    float* KGL = ws + 5 * SZ;
    float* VGL = KGL + 16384;
    float* GQ  = VGL + 16384;
    float* QG  = GQ + 16384;
    float* OG  = QG + 16384;
    float* GLN = OG + 16384;
    float* GH  = GLN + 16384;
    float* A2  = GH + 65536;
    float* OGP = A2 + KGSZ;

    dim3 blk(256);
    const float* wkpe = sa_wk + 256 * 256;   // rows 256..287 of (288,256)
    const float* wvpe = sa_wv + 256 * 256;

    // LN1 (spatial) and LN3 (glob)
    ln_rows_k<<<dim3(4096), blk, 0, stream>>>(latents, ln1g, ln1b, X, LS, ROWS_B, 0, LS, LS, 0);
    ln_rows_k<<<dim3(64),   blk, 0, stream>>>(latents, ln3g, ln3b, GQ, NG, ROWS_B, LS, NG, NG, 0);

    // projections
    gemm_k<0,0,0><<<dim3(4,64), blk, 0, stream>>>(X, sa_wq, nullptr, nullptr, Qb, 4096,256,256, 4096,4096,0, 4096,4096,0);
    gemm_k<0,0,0><<<dim3(4,64), blk, 0, stream>>>(X, sa_wk, nullptr, nullptr, XK, 4096,256,256, 4096,4096,0, 4096,4096,0);
    gemm_k<0,0,0><<<dim3(4,64), blk, 0, stream>>>(X, sa_wv, nullptr, nullptr, XV, 4096,256,256, 4096,4096,0, 4096,4096,0);
    gemm_k<0,0,0><<<dim3(4,1),  blk, 0, stream>>>(latents, sa_wk, nullptr, nullptr, KGL, 64,256,256, NG,ROWS_B,LS, 64,64,0);
    gemm_k<0,0,0><<<dim3(4,1),  blk, 0, stream>>>(latents, sa_wv, nullptr, nullptr, VGL, 64,256,256, NG,ROWS_B,LS, 64,64,0);

    // fused spatial attention -> O
    attn_sp_k<<<dim3(4096), blk, 0, stream>>>(Qb, XK, XV, KGL, VGL, idx, rpe, srpe, dist,
                                              wkpe, wvpe, lsig, gbias, O);

    // spatial residual: d_out[:, :LS] = latents + O@wo + bo
    gemm_k<1,0,1><<<dim3(4,64), blk, 0, stream>>>(O, sa_wo, sa_bo, latents, out, 4096,256,256, 4096,4096,0, LS,ROWS_B,0);

    // spatial FF
    ln_rows_k<<<dim3(4096), blk, 0, stream>>>(out, ln2g, ln2b, X, LS, ROWS_B, 0, LS, LS, 0);
    gemm_k<1,1,0><<<dim3(16,64), blk, 0, stream>>>(X, sff_w1, sff_b1, nullptr, H1, 4096,1024,256, 4096,4096,0, 4096,4096,0);
    gemm_k<1,0,1><<<dim3(4,64),  blk, 0, stream>>>(H1, sff_w2, sff_b2, out, out, 4096,256,1024, 4096,4096,0, LS,ROWS_B,0);

    // global attention projections (kv = [spatial_new ; gq_in])
    gemm_k<0,0,0><<<dim3(4,64), blk, 0, stream>>>(out, ga_wk, nullptr, nullptr, KG, 4096,256,256, LS,ROWS_B,0, LS,ROWS_B,0);
    gemm_k<0,0,0><<<dim3(4,1),  blk, 0, stream>>>(GQ,  ga_wk, nullptr, nullptr, KG, 64,256,256, 64,64,0, NG,ROWS_B,LS);
    gemm_k<0,0,0><<<dim3(4,64), blk, 0, stream>>>(out, ga_wv, nullptr, nullptr, VG, 4096,256,256, LS,ROWS_B,0, LS,ROWS_B,0);
    gemm_k<0,0,0><<<dim3(4,1),  blk, 0, stream>>>(GQ,  ga_wv, nullptr, nullptr, VG, 64,256,256, 64,64,0, NG,ROWS_B,LS);
    gemm_k<0,0,0><<<dim3(4,1),  blk, 0, stream>>>(GQ,  ga_wq, nullptr, nullptr, QG, 64,256,256, 64,64,0, 64,64,0);

    ga_scores_k<<<dim3(2 * ROWS_B), blk, 0, stream>>>(QG, KG, A2);
    ga_softmax_k<<<dim3(512), blk, 0, stream>>>(A2);
    ga_wv_k<<<dim3(64, 8), blk, 0, stream>>>(A2, VG, OGP);
    ga_red_k<<<dim3(64), blk, 0, stream>>>(OGP, OG);

    // glob residual
    gemm_k<1,0,1><<<dim3(4,1), blk, 0, stream>>>(OG, ga_wo, ga_bo, latents, out, 64,256,256, 64,64,0, NG,ROWS_B,LS);

    // glob FF
    ln_rows_k<<<dim3(64), blk, 0, stream>>>(out, ln4g, ln4b, GLN, NG, ROWS_B, LS, NG, NG, 0);
    gemm_k<1,1,0><<<dim3(16,1), blk, 0, stream>>>(GLN, gff_w1, gff_b1, nullptr, GH, 64,1024,256, 64,64,0, 64,64,0);
    gemm_k<1,0,1><<<dim3(4,1),  blk, 0, stream>>>(GH, gff_w2, gff_b2, out, out, 64,256,1024, 64,64,0, NG,ROWS_B,LS);
}

// Round 3
// 464.763 us; speedup vs baseline: 1.3771x; 1.1053x over previous
//
#include <hip/hip_runtime.h>
#include <math.h>

// Shapes (hardcoded from reference)
// B=2, LS=2048, G=32, KNN=16, DIM=256, PE=32, H=8, DH=32, INNER=256, FF=1024
#define LS 2048
#define NG 32
#define ROWS_B 2080      // LS+G
#define DIM 256
#define PE 32
#define NH 8
#define DH 32
#define FFD 1024
#define NCTX 49          // 1 + KNN + G
#define SCALE 0.17677669529663687f  // 1/sqrt(32)

typedef __attribute__((ext_vector_type(8))) short short8;
typedef __attribute__((ext_vector_type(4))) float f32x4;
typedef __attribute__((ext_vector_type(4))) unsigned short us4;

__device__ __forceinline__ unsigned short f2bf(float x)
{
    unsigned int u = __float_as_uint(x);
    unsigned int r = (u + 0x7fffu + ((u >> 16) & 1u)) >> 16;
    return (unsigned short)r;
}

// ---------------- LayerNorm over 256-wide rows ----------------
__global__ __launch_bounds__(256) void ln_rows_k(
    const float* __restrict__ in, const float* __restrict__ gam,
    const float* __restrict__ bet, float* __restrict__ out,
    int irpb, int ibsr, int ioff, int orpb, int obsr, int ooff)
{
    __shared__ float red[8];
    int r = blockIdx.x, t = threadIdx.x;
    size_t ip = ((size_t)(r / irpb) * ibsr + ioff + (r % irpb)) * DIM + t;
    size_t op = ((size_t)(r / orpb) * obsr + ooff + (r % orpb)) * DIM + t;
    float v = in[ip];
    float a = v, b2 = v * v;
    #pragma unroll
    for (int m = 32; m >= 1; m >>= 1) {
        a  += __shfl_xor(a, m);
        b2 += __shfl_xor(b2, m);
    }
    if ((t & 63) == 0) { red[t >> 6] = a; red[4 + (t >> 6)] = b2; }
    __syncthreads();
    float mean = (red[0] + red[1] + red[2] + red[3]) * (1.0f / 256.0f);
    float var  = (red[4] + red[5] + red[6] + red[7]) * (1.0f / 256.0f) - mean * mean;
    out[op] = (v - mean) * rsqrtf(var + 1e-5f) * gam[t] + bet[t];
}

// ---------------- GELU (tanh approx, matches jax.nn.gelu default) ----------------
__device__ __forceinline__ float gelu_f(float x)
{
    float x3 = x * x * x;
    return 0.5f * x * (1.0f + tanhf(0.7978845608028654f * (x + 0.044715f * x3)));
}

// ---------------- weight transpose + f32->bf16 convert:  Wt[n][k] = bf16(W[k][n]) ----
// grid (N/64, K/64), 256 threads
__global__ __launch_bounds__(256) void wconv_k(
    const float* __restrict__ W, unsigned short* __restrict__ Wt, int K, int N)
{
    __shared__ unsigned short tile[64][72];
    int t = threadIdx.x;
    int n0 = blockIdx.x * 64, k0 = blockIdx.y * 64;
    #pragma unroll
    for (int r = 0; r < 4; ++r) {
        int k = r * 16 + (t >> 4);
        int n = (t & 15) * 4;
        float4 wv = *(const float4*)(W + (size_t)(k0 + k) * N + n0 + n);
        tile[k][n + 0] = f2bf(wv.x);
        tile[k][n + 1] = f2bf(wv.y);
        tile[k][n + 2] = f2bf(wv.z);
        tile[k][n + 3] = f2bf(wv.w);
    }
    __syncthreads();
    #pragma unroll
    for (int r = 0; r < 4; ++r) {
        int n = r * 16 + (t >> 4);
        int k = (t & 15) * 4;
        us4 o;
        o.x = tile[k + 0][n];
        o.y = tile[k + 1][n];
        o.z = tile[k + 2][n];
        o.w = tile[k + 3][n];
        *(us4*)(Wt + (size_t)(n0 + n) * K + k0 + k) = o;
    }
}

// ---------------- bf16 MFMA GEMM: C[map] = (RES?Res:0) + act(A[map]@B + bias) -------
// 64x64x64 tiles, 256 thr = 4 waves (2x2 quadrants of 32x32), 16x16x32 bf16 MFMA.
// A: f32 global, converted during staging. Bt: bf16 pre-transposed [N][K].
// LDS tiles XOR-swizzled in 16B slots (slot ^= row&7) -> conflict-free b128 frag reads.
template<int BIAS, int DOGELU, int RES>
__global__ __launch_bounds__(256) void mgemm_k(
    const float* __restrict__ A, const unsigned short* __restrict__ Bt,
    const float* __restrict__ bias, const float* __restrict__ Res,
    float* __restrict__ C, int M, int N, int K,
    int arpb, int absr, int aoff, int crpb, int cbsr, int coff)
{
    __shared__ unsigned short Asl[64][64];
    __shared__ unsigned short Bsl[64][64];
    int t = threadIdx.x;
    int col0 = blockIdx.x * 64, row0 = blockIdx.y * 64;
    int lane = t & 63, w = t >> 6;
    int wr = w >> 1, wc = w & 1;
    int lrow = lane & 15, lk = lane >> 4;

    int srow = t >> 4;             // 0..15
    int scol = (t & 15) << 2;      // 0..60 step 4
    int sslot = (t & 15) >> 1;     // 16B slot index 0..7
    int shalf = (t & 15) & 1;      // which half of the slot

    f32x4 acc[2][2];
    #pragma unroll
    for (int m = 0; m < 2; ++m)
        #pragma unroll
        for (int n = 0; n < 2; ++n)
            acc[m][n] = (f32x4){0.f, 0.f, 0.f, 0.f};

    for (int kk = 0; kk < K; kk += 64) {
        #pragma unroll
        for (int r = 0; r < 4; ++r) {
            int row = r * 16 + srow;
            int ar = row0 + row;
            size_t ab = ((size_t)(ar / arpb) * absr + aoff + (ar % arpb)) * (size_t)K + kk + scol;
            float4 av = *(const float4*)(A + ab);
            us4 ap;
            ap.x = f2bf(av.x); ap.y = f2bf(av.y); ap.z = f2bf(av.z); ap.w = f2bf(av.w);
            *(us4*)&Asl[row][((sslot ^ (row & 7)) << 3) + (shalf << 2)] = ap;
            us4 bv = *(const us4*)(Bt + (size_t)(col0 + row) * K + kk + scol);
            *(us4*)&Bsl[row][((sslot ^ (row & 7)) << 3) + (shalf << 2)] = bv;
        }
        __syncthreads();
        #pragma unroll
        for (int k2 = 0; k2 < 2; ++k2) {
            short8 af[2], bfr[2];
            #pragma unroll
            for (int m = 0; m < 2; ++m) {
                int rowA = wr * 32 + m * 16 + lrow;
                af[m] = *(short8*)&Asl[rowA][((k2 * 4 + lk) ^ (rowA & 7)) << 3];
                int rowB = wc * 32 + m * 16 + lrow;
                bfr[m] = *(short8*)&Bsl[rowB][((k2 * 4 + lk) ^ (rowB & 7)) << 3];
            }
            #pragma unroll
            for (int m = 0; m < 2; ++m)
                #pragma unroll
                for (int n = 0; n < 2; ++n)
                    acc[m][n] = __builtin_amdgcn_mfma_f32_16x16x32_bf16(af[m], bfr[n], acc[m][n], 0, 0, 0);
        }
        __syncthreads();
    }
    #pragma unroll
    for (int m = 0; m < 2; ++m) {
        #pragma unroll
        for (int n = 0; n < 2; ++n) {
            int col = col0 + wc * 32 + n * 16 + lrow;
            #pragma unroll
            for (int j = 0; j < 4; ++j) {
                int r = row0 + wr * 32 + m * 16 + lk * 4 + j;
                size_t cp = ((size_t)(r / crpb) * cbsr + coff + (r % crpb)) * (size_t)N + col;
                float o = acc[m][n][j];
                if (BIAS)   o += bias[col];
                if (DOGELU) o = gelu_f(o);
                if (RES)    o += Res[cp];
                C[cp] = o;
            }
        }
    }
}

// ---------------- f32 tiled GEMM (small M=64 cases only) ----------------
template<int BIAS, int DOGELU, int RES>
__global__ __launch_bounds__(256) void gemm_k(
    const float* __restrict__ A, const float* __restrict__ Bm,
    const float* __restrict__ bias, const float* __restrict__ Res,
    float* __restrict__ C, int M, int N, int K,
    int arpb, int absr, int aoff, int crpb, int cbsr, int coff)
{
    __shared__ float As[16][68];
    __shared__ float Bs[16][64];
    int t = threadIdx.x;
    int col0 = blockIdx.x * 64, row0 = blockIdx.y * 64;
    int tx = t & 15, ty = t >> 4;
    int la_r = t >> 2, la_c = (t & 3) << 2;
    int ar = row0 + la_r;
    size_t a_base = ((size_t)(ar / arpb) * absr + aoff + (ar % arpb)) * (size_t)K;
    float acc[4][4] = {};
    for (int kk = 0; kk < K; kk += 16) {
        float4 av = *(const float4*)(A + a_base + kk + la_c);
        float4 bv = *(const float4*)(Bm + (size_t)(kk + ty) * N + col0 + (tx << 2));
        As[la_c + 0][la_r] = av.x;
        As[la_c + 1][la_r] = av.y;
        As[la_c + 2][la_r] = av.z;
        As[la_c + 3][la_r] = av.w;
        *(float4*)&Bs[ty][tx << 2] = bv;
        __syncthreads();
        #pragma unroll
        for (int k = 0; k < 16; ++k) {
            float4 a = *(float4*)&As[k][ty << 2];
            float4 b = *(float4*)&Bs[k][tx << 2];
            acc[0][0] += a.x * b.x; acc[0][1] += a.x * b.y; acc[0][2] += a.x * b.z; acc[0][3] += a.x * b.w;
            acc[1][0] += a.y * b.x; acc[1][1] += a.y * b.y; acc[1][2] += a.y * b.z; acc[1][3] += a.y * b.w;
            acc[2][0] += a.z * b.x; acc[2][1] += a.z * b.y; acc[2][2] += a.z * b.z; acc[2][3] += a.z * b.w;
            acc[3][0] += a.w * b.x; acc[3][1] += a.w * b.y; acc[3][2] += a.w * b.z; acc[3][3] += a.w * b.w;
        }
        __syncthreads();
    }
    #pragma unroll
    for (int i = 0; i < 4; ++i) {
        int r = row0 + (ty << 2) + i;
        size_t cp = ((size_t)(r / crpb) * cbsr + coff + (r % crpb)) * (size_t)N + col0 + (tx << 2);
        #pragma unroll
        for (int j = 0; j < 4; ++j) {
            float o = acc[i][j];
            if (BIAS)   o += bias[col0 + (tx << 2) + j];
            if (DOGELU) o = gelu_f(o);
            if (RES)    o += Res[cp + j];
            C[cp + j] = o;
        }
    }
}

// ---------------- fused spatial attention, online softmax ----------------
__global__ __launch_bounds__(256) void attn_sp_k(
    const float* __restrict__ Q, const float* __restrict__ XK,
    const float* __restrict__ XV, const float* __restrict__ KGL,
    const float* __restrict__ VGL, const int* __restrict__ idx,
    const float* __restrict__ rpe, const float* __restrict__ srpe,
    const float* __restrict__ dist, const float* __restrict__ wkpe,
    const float* __restrict__ wvpe, const float* __restrict__ lsig,
    const float* __restrict__ gbias, float* __restrict__ O)
{
    __shared__ float s_rpe[17 * 32];
    __shared__ int   s_idx[16];
    int t = threadIdx.x;
    int r = blockIdx.x;          // b*LS + l
    int h = t >> 5, d = t & 31;
    int b = r >> 11;
    size_t rbase = (size_t)r * 256;

    if (t < 32) s_rpe[t] = srpe[(size_t)r * 32 + t];
    for (int i = t; i < 512; i += 256) s_rpe[32 + i] = rpe[(size_t)r * 512 + i];
    if (t < 16) s_idx[t] = idx[r * 16 + t];

    float qt = Q[rbase + t];
    float inv2s = 1.0f / (2.0f * __expf(2.0f * lsig[h]));
    float gb = gbias[0];

    float qw = 0.0f;
    #pragma unroll
    for (int p = 0; p < 32; ++p) {
        float part = qt * wkpe[p * 256 + t];
        part += __shfl_xor(part, 16); part += __shfl_xor(part, 8);
        part += __shfl_xor(part, 4);  part += __shfl_xor(part, 2);
        part += __shfl_xor(part, 1);
        if (d == p) qw = part;
    }
    __syncthreads();

    float m = -3.0e38f, l = 0.0f, acc = 0.0f, r_acc = 0.0f;

    for (int c = 0; c < 17; ++c) {
        int row = (c == 0) ? r : ((b << 11) + s_idx[c - 1]);
        size_t rb = (size_t)row * 256 + t;
        float kt = XK[rb];
        float vt = XV[rb];
        float rv = s_rpe[c * 32 + d];
        float part = qt * kt + rv * qw;
        part += __shfl_xor(part, 16); part += __shfl_xor(part, 8);
        part += __shfl_xor(part, 4);  part += __shfl_xor(part, 2);
        part += __shfl_xor(part, 1);
        float bia = 0.0f;
        if (c > 0) {
            float dd = dist[(size_t)r * 16 + (c - 1)];
            bia = -dd * dd * inv2s;
        }
        float s = part * SCALE + bia;
        float m_new = fmaxf(m, s);
        float corr = __expf(m - m_new);
        float p = __expf(s - m_new);
        l = l * corr + p;
        acc = acc * corr + p * vt;
        r_acc = r_acc * corr + p * rv;
        m = m_new;
    }
    for (int c = 0; c < NG; ++c) {
        size_t gb2 = ((size_t)(b * NG + c)) * 256 + t;
        float kt = KGL[gb2];
        float vt = VGL[gb2];
        float part = qt * kt;
        part += __shfl_xor(part, 16); part += __shfl_xor(part, 8);
        part += __shfl_xor(part, 4);  part += __shfl_xor(part, 2);
        part += __shfl_xor(part, 1);
        float s = part * SCALE + gb;
        float m_new = fmaxf(m, s);
        float corr = __expf(m - m_new);
        float p = __expf(s - m_new);
        l = l * corr + p;
        acc = acc * corr + p * vt;
        m = m_new;
    }

    float vo = acc;
    #pragma unroll
    for (int p = 0; p < 32; ++p) {
        float rp = __shfl(r_acc, p, 32);
        vo += rp * wvpe[p * 256 + t];
    }
    O[rbase + t] = vo / l;
}

// ---------------- global attention: scores ----------------
__global__ __launch_bounds__(256) void ga_scores_k(
    const float* __restrict__ QG, const float* __restrict__ KG, float* __restrict__ A2)
{
    int t = threadIdx.x;
    int blk = blockIdx.x;           // b*2080 + c
    int b = blk / ROWS_B, c = blk % ROWS_B;
    int h = t >> 5, d = t & 31;
    float kt = KG[(size_t)blk * 256 + t];
    for (int g = 0; g < NG; ++g) {
        float ps = QG[((size_t)(b * NG + g)) * 256 + t] * kt;
        ps += __shfl_xor(ps, 16); ps += __shfl_xor(ps, 8); ps += __shfl_xor(ps, 4);
        ps += __shfl_xor(ps, 2);  ps += __shfl_xor(ps, 1);
        if (d == 0) A2[((size_t)(b * NH + h) * NG + g) * ROWS_B + c] = ps * SCALE;
    }
}

// ---------------- global attention: row softmax over 2080 ----------------
__global__ __launch_bounds__(256) void ga_softmax_k(float* __restrict__ A2)
{
    __shared__ float red[8];
    int t = threadIdx.x;
    float* row = A2 + (size_t)blockIdx.x * ROWS_B;
    float lm = -1e30f;
    for (int i = t; i < ROWS_B; i += 256) lm = fmaxf(lm, row[i]);
    #pragma unroll
    for (int m = 32; m >= 1; m >>= 1) lm = fmaxf(lm, __shfl_xor(lm, m));
    if ((t & 63) == 0) red[t >> 6] = lm;
    __syncthreads();
    float M = fmaxf(fmaxf(red[0], red[1]), fmaxf(red[2], red[3]));
    float ls = 0.0f;
    for (int i = t; i < ROWS_B; i += 256) {
        float e = __expf(row[i] - M);
        row[i] = e;
        ls += e;
    }
    #pragma unroll
    for (int m = 32; m >= 1; m >>= 1) ls += __shfl_xor(ls, m);
    if ((t & 63) == 0) red[4 + (t >> 6)] = ls;
    __syncthreads();
    float inv = 1.0f / (red[4] + red[5] + red[6] + red[7]);
    for (int i = t; i < ROWS_B; i += 256) row[i] *= inv;
}

// ---------------- global attention: weighted V (split-K over keys) ----------------
__global__ __launch_bounds__(256) void ga_wv_k(
    const float* __restrict__ A2, const float* __restrict__ VG, float* __restrict__ OGP)
{
    int t = threadIdx.x;
    int bg = blockIdx.x;       // b*32+g
    int s = blockIdx.y;        // 0..7
    int b = bg >> 5, g = bg & 31;
    int h = t >> 5;
    const float* w = A2 + ((size_t)(b * NH + h) * NG + g) * ROWS_B;
    const float* v = VG + (size_t)b * ROWS_B * 256;
    float acc = 0.0f;
    int c0 = s * 260, c1 = c0 + 260;
    for (int c = c0; c < c1; ++c) acc += w[c] * v[(size_t)c * 256 + t];
    OGP[((size_t)bg * 8 + s) * 256 + t] = acc;
}

__global__ __launch_bounds__(256) void ga_red_k(
    const float* __restrict__ OGP, float* __restrict__ OG)
{
    int t = threadIdx.x, bg = blockIdx.x;
    float a = 0.0f;
    #pragma unroll
    for (int s = 0; s < 8; ++s) a += OGP[((size_t)bg * 8 + s) * 256 + t];
    OG[(size_t)bg * 256 + t] = a;
}

// ---------------- launch ----------------
extern "C" void kernel_launch(void* const* d_in, const int* in_sizes, int n_in,
                              void* d_out, int out_size, void* d_ws, size_t ws_size,
                              hipStream_t stream)
{
    const float* latents = (const float*)d_in[0];
    const int*   idx     = (const int*)d_in[1];
    const float* rpe     = (const float*)d_in[2];
    const float* srpe    = (const float*)d_in[3];
    const float* dist    = (const float*)d_in[4];
    const float* sa_wq   = (const float*)d_in[6];
    const float* sa_wk   = (const float*)d_in[7];
    const float* sa_wv   = (const float*)d_in[8];
    const float* sa_wo   = (const float*)d_in[9];
    const float* sa_bo   = (const float*)d_in[10];
    const float* lsig    = (const float*)d_in[11];
    const float* gbias   = (const float*)d_in[12];
    const float* ln1g    = (const float*)d_in[13];
    const float* ln1b    = (const float*)d_in[14];
    const float* ln2g    = (const float*)d_in[15];
    const float* ln2b    = (const float*)d_in[16];
    const float* sff_w1  = (const float*)d_in[17];
    const float* sff_b1  = (const float*)d_in[18];
    const float* sff_w2  = (const float*)d_in[19];
    const float* sff_b2  = (const float*)d_in[20];
    const float* ga_wq   = (const float*)d_in[21];
    const float* ga_wk   = (const float*)d_in[22];
    const float* ga_wv   = (const float*)d_in[23];
    const float* ga_wo   = (const float*)d_in[24];
    const float* ga_bo   = (const float*)d_in[25];
    const float* ln3g    = (const float*)d_in[27];
    const float* ln3b    = (const float*)d_in[28];
    const float* ln4g    = (const float*)d_in[29];
    const float* ln4b    = (const float*)d_in[30];
    const float* gff_w1  = (const float*)d_in[31];
    const float* gff_b1  = (const float*)d_in[32];
    const float* gff_w2  = (const float*)d_in[33];
    const float* gff_b2  = (const float*)d_in[34];
    float* out = (float*)d_out;

    const size_t SZ   = (size_t)4096 * 256;       // 1,048,576
    const size_t KGSZ = (size_t)2 * ROWS_B * 256; // 1,064,960
    float* ws  = (float*)d_ws;
    float* X   = ws;                 // LN1 out, later LN2 out
    float* Qb  = ws + SZ;
    float* XK  = ws + 2 * SZ;
    float* XV  = ws + 3 * SZ;
    float* O   = ws + 4 * SZ;
    float* H1  = ws + SZ;            // overlays Qb..O after attention
    float* KG  = ws + SZ;            // overlays H1 after ff2
    float* VG  = KG + KGSZ;
    float* KGL = ws + 5 * SZ;
    float* VGL = KGL + 16384;
    float* GQ  = VGL + 16384;
    float* QG  = GQ + 16384;
    float* OG  = QG + 16384;
    float* GLN = OG + 16384;
    float* GH  = GLN + 16384;
    float* A2  = GH + 65536;
    float* OGP = A2 + KGSZ;

    // bf16 transposed weights overlay A2 (A2 is first written by ga_scores,
    // which runs after the last mgemm that reads these).
    unsigned short* wt_saq = (unsigned short*)A2;
    unsigned short* wt_sak = wt_saq + 65536;
    unsigned short* wt_sav = wt_sak + 65536;
    unsigned short* wt_sao = wt_sav + 65536;
    unsigned short* wt_ff1 = wt_sao + 65536;
    unsigned short* wt_ff2 = wt_ff1 + 262144;
    unsigned short* wt_gak = wt_ff2 + 262144;
    unsigned short* wt_gav = wt_gak + 65536;

    dim3 blk(256);
    const float* wkpe = sa_wk + 256 * 256;   // rows 256..287 of (288,256)
    const float* wvpe = sa_wv + 256 * 256;

    // weight prep (bf16 transpose)
    wconv_k<<<dim3(4,4),  blk, 0, stream>>>(sa_wq,  wt_saq, 256, 256);
    wconv_k<<<dim3(4,4),  blk, 0, stream>>>(sa_wk,  wt_sak, 256, 256);
    wconv_k<<<dim3(4,4),  blk, 0, stream>>>(sa_wv,  wt_sav, 256, 256);
    wconv_k<<<dim3(4,4),  blk, 0, stream>>>(sa_wo,  wt_sao, 256, 256);
    wconv_k<<<dim3(16,4), blk, 0, stream>>>(sff_w1, wt_ff1, 256, 1024);
    wconv_k<<<dim3(4,16), blk, 0, stream>>>(sff_w2, wt_ff2, 1024, 256);
    wconv_k<<<dim3(4,4),  blk, 0, stream>>>(ga_wk,  wt_gak, 256, 256);
    wconv_k<<<dim3(4,4),  blk, 0, stream>>>(ga_wv,  wt_gav, 256, 256);

    // LN1 (spatial) and LN3 (glob)
    ln_rows_k<<<dim3(4096), blk, 0, stream>>>(latents, ln1g, ln1b, X, LS, ROWS_B, 0, LS, LS, 0);
    ln_rows_k<<<dim3(64),   blk, 0, stream>>>(latents, ln3g, ln3b, GQ, NG, ROWS_B, LS, NG, NG, 0);

    // projections (bf16 MFMA)
    mgemm_k<0,0,0><<<dim3(4,64), blk, 0, stream>>>(X, wt_saq, nullptr, nullptr, Qb, 4096,256,256, 4096,4096,0, 4096,4096,0);
    mgemm_k<0,0,0><<<dim3(4,64), blk, 0, stream>>>(X, wt_sak, nullptr, nullptr, XK, 4096,256,256, 4096,4096,0, 4096,4096,0);
    mgemm_k<0,0,0><<<dim3(4,64), blk, 0, stream>>>(X, wt_sav, nullptr, nullptr, XV, 4096,256,256, 4096,4096,0, 4096,4096,0);
    gemm_k<0,0,0><<<dim3(4,1),  blk, 0, stream>>>(latents, sa_wk, nullptr, nullptr, KGL, 64,256,256, NG,ROWS_B,LS, 64,64,0);
    gemm_k<0,0,0><<<dim3(4,1),  blk, 0, stream>>>(latents, sa_wv, nullptr, nullptr, VGL, 64,256,256, NG,ROWS_B,LS, 64,64,0);

    // fused spatial attention -> O
    attn_sp_k<<<dim3(4096), blk, 0, stream>>>(Qb, XK, XV, KGL, VGL, idx, rpe, srpe, dist,
                                              wkpe, wvpe, lsig, gbias, O);

    // spatial residual: d_out[:, :LS] = latents + O@wo + bo
    mgemm_k<1,0,1><<<dim3(4,64), blk, 0, stream>>>(O, wt_sao, sa_bo, latents, out, 4096,256,256, 4096,4096,0, LS,ROWS_B,0);

    // spatial FF
    ln_rows_k<<<dim3(4096), blk, 0, stream>>>(out, ln2g, ln2b, X, LS, ROWS_B, 0, LS, LS, 0);
    mgemm_k<1,1,0><<<dim3(16,64), blk, 0, stream>>>(X, wt_ff1, sff_b1, nullptr, H1, 4096,1024,256, 4096,4096,0, 4096,4096,0);
    mgemm_k<1,0,1><<<dim3(4,64),  blk, 0, stream>>>(H1, wt_ff2, sff_b2, out, out, 4096,256,1024, 4096,4096,0, LS,ROWS_B,0);

    // global attention projections (kv = [spatial_new ; gq_in])
    mgemm_k<0,0,0><<<dim3(4,64), blk, 0, stream>>>(out, wt_gak, nullptr, nullptr, KG, 4096,256,256, LS,ROWS_B,0, LS,ROWS_B,0);
    gemm_k<0,0,0><<<dim3(4,1),  blk, 0, stream>>>(GQ,  ga_wk, nullptr, nullptr, KG, 64,256,256, 64,64,0, NG,ROWS_B,LS);
    mgemm_k<0,0,0><<<dim3(4,64), blk, 0, stream>>>(out, wt_gav, nullptr, nullptr, VG, 4096,256,256, LS,ROWS_B,0, LS,ROWS_B,0);
    gemm_k<0,0,0><<<dim3(4,1),  blk, 0, stream>>>(GQ,  ga_wv, nullptr, nullptr, VG, 64,256,256, 64,64,0, NG,ROWS_B,LS);
    gemm_k<0,0,0><<<dim3(4,1),  blk, 0, stream>>>(GQ,  ga_wq, nullptr, nullptr, QG, 64,256,256, 64,64,0, 64,64,0);

    ga_scores_k<<<dim3(2 * ROWS_B), blk, 0, stream>>>(QG, KG, A2);
    ga_softmax_k<<<dim3(512), blk, 0, stream>>>(A2);
    ga_wv_k<<<dim3(64, 8), blk, 0, stream>>>(A2, VG, OGP);
    ga_red_k<<<dim3(64), blk, 0, stream>>>(OGP, OG);

    // glob residual
    gemm_k<1,0,1><<<dim3(4,1), blk, 0, stream>>>(OG, ga_wo, ga_bo, latents, out, 64,256,256, 64,64,0, NG,ROWS_B,LS);

    // glob FF
    ln_rows_k<<<dim3(64), blk, 0, stream>>>(out, ln4g, ln4b, GLN, NG, ROWS_B, LS, NG, NG, 0);
    gemm_k<1,1,0><<<dim3(16,1), blk, 0, stream>>>(GLN, gff_w1, gff_b1, nullptr, GH, 64,1024,256, 64,64,0, 64,64,0);
    gemm_k<1,0,1><<<dim3(4,1),  blk, 0, stream>>>(GH, gff_w2, gff_b2, out, out, 64,256,1024, 64,64,0, NG,ROWS_B,LS);
}

// Round 4
// 361.380 us; speedup vs baseline: 1.7711x; 1.2861x over previous
//
#include <hip/hip_runtime.h>
#include <math.h>

// Shapes (hardcoded from reference)
// B=2, LS=2048, G=32, KNN=16, DIM=256, PE=32, H=8, DH=32, INNER=256, FF=1024
#define LS 2048
#define NG 32
#define ROWS_B 2080      // LS+G
#define DIM 256
#define PE 32
#define NH 8
#define DH 32
#define FFD 1024
#define NCTX 49          // 1 + KNN + G
#define SCALE 0.17677669529663687f  // 1/sqrt(32)

typedef __attribute__((ext_vector_type(8))) short short8;
typedef __attribute__((ext_vector_type(4))) float f32x4;
typedef __attribute__((ext_vector_type(4))) unsigned short us4;

__device__ __forceinline__ unsigned short f2bf(float x)
{
    unsigned int u = __float_as_uint(x);
    unsigned int r = (u + 0x7fffu + ((u >> 16) & 1u)) >> 16;
    return (unsigned short)r;
}

// ---------------- LayerNorm over 256-wide rows ----------------
__global__ __launch_bounds__(256) void ln_rows_k(
    const float* __restrict__ in, const float* __restrict__ gam,
    const float* __restrict__ bet, float* __restrict__ out,
    int irpb, int ibsr, int ioff, int orpb, int obsr, int ooff)
{
    __shared__ float red[8];
    int r = blockIdx.x, t = threadIdx.x;
    size_t ip = ((size_t)(r / irpb) * ibsr + ioff + (r % irpb)) * DIM + t;
    size_t op = ((size_t)(r / orpb) * obsr + ooff + (r % orpb)) * DIM + t;
    float v = in[ip];
    float a = v, b2 = v * v;
    #pragma unroll
    for (int m = 32; m >= 1; m >>= 1) {
        a  += __shfl_xor(a, m);
        b2 += __shfl_xor(b2, m);
    }
    if ((t & 63) == 0) { red[t >> 6] = a; red[4 + (t >> 6)] = b2; }
    __syncthreads();
    float mean = (red[0] + red[1] + red[2] + red[3]) * (1.0f / 256.0f);
    float var  = (red[4] + red[5] + red[6] + red[7]) * (1.0f / 256.0f) - mean * mean;
    out[op] = (v - mean) * rsqrtf(var + 1e-5f) * gam[t] + bet[t];
}

// ---------------- GELU ----------------
__device__ __forceinline__ float gelu_f(float x)
{
    float x3 = x * x * x;
    return 0.5f * x * (1.0f + tanhf(0.7978845608028654f * (x + 0.044715f * x3)));
}

// ---------------- batched weight transpose+convert ----------------
struct WEnt { const float* src; unsigned short* dst; int K; int N; int t0; };
struct WTab { WEnt e[9]; };

__global__ __launch_bounds__(256) void wconv_all_k(WTab tab)
{
    __shared__ unsigned short tile[64][72];
    int blk = blockIdx.x;
    int i = 0;
    #pragma unroll
    for (int j = 1; j < 9; ++j) if (blk >= tab.e[j].t0) i = j;
    const float* W = tab.e[i].src;
    unsigned short* Wt = tab.e[i].dst;
    int K = tab.e[i].K, N = tab.e[i].N;
    int local = blk - tab.e[i].t0;
    int nb = N >> 6;
    int n0 = (local % nb) * 64, k0 = (local / nb) * 64;
    int t = threadIdx.x;
    #pragma unroll
    for (int r = 0; r < 4; ++r) {
        int k = r * 16 + (t >> 4);
        int n = (t & 15) * 4;
        float4 wv = *(const float4*)(W + (size_t)(k0 + k) * N + n0 + n);
        tile[k][n + 0] = f2bf(wv.x);
        tile[k][n + 1] = f2bf(wv.y);
        tile[k][n + 2] = f2bf(wv.z);
        tile[k][n + 3] = f2bf(wv.w);
    }
    __syncthreads();
    #pragma unroll
    for (int r = 0; r < 4; ++r) {
        int n = r * 16 + (t >> 4);
        int k = (t & 15) * 4;
        us4 o;
        o.x = tile[k + 0][n];
        o.y = tile[k + 1][n];
        o.z = tile[k + 2][n];
        o.w = tile[k + 3][n];
        *(us4*)(Wt + (size_t)(n0 + n) * K + k0 + k) = o;
    }
}

// ---------------- bf16 MFMA GEMM ----------------
// 64x64x64 tiles, 256 thr = 4 waves (2x2 quadrants of 32x32), 16x16x32 bf16 MFMA.
// A: f32 global, converted during staging. Bt: bf16 pre-transposed [N][K].
template<int BIAS, int DOGELU, int RES>
__global__ __launch_bounds__(256) void mgemm_k(
    const float* __restrict__ A, const unsigned short* __restrict__ Bt,
    const float* __restrict__ bias, const float* __restrict__ Res,
    float* __restrict__ C, int M, int N, int K,
    int arpb, int absr, int aoff, int crpb, int cbsr, int coff)
{
    __shared__ unsigned short Asl[64][64];
    __shared__ unsigned short Bsl[64][64];
    int t = threadIdx.x;
    int col0 = blockIdx.x * 64, row0 = blockIdx.y * 64;
    int lane = t & 63, w = t >> 6;
    int wr = w >> 1, wc = w & 1;
    int lrow = lane & 15, lk = lane >> 4;

    int srow = t >> 4;
    int scol = (t & 15) << 2;
    int sslot = (t & 15) >> 1;
    int shalf = (t & 15) & 1;

    f32x4 acc[2][2];
    #pragma unroll
    for (int m = 0; m < 2; ++m)
        #pragma unroll
        for (int n = 0; n < 2; ++n)
            acc[m][n] = (f32x4){0.f, 0.f, 0.f, 0.f};

    for (int kk = 0; kk < K; kk += 64) {
        #pragma unroll
        for (int r = 0; r < 4; ++r) {
            int row = r * 16 + srow;
            int ar = row0 + row;
            size_t ab = ((size_t)(ar / arpb) * absr + aoff + (ar % arpb)) * (size_t)K + kk + scol;
            float4 av = *(const float4*)(A + ab);
            us4 ap;
            ap.x = f2bf(av.x); ap.y = f2bf(av.y); ap.z = f2bf(av.z); ap.w = f2bf(av.w);
            *(us4*)&Asl[row][((sslot ^ (row & 7)) << 3) + (shalf << 2)] = ap;
            us4 bv = *(const us4*)(Bt + (size_t)(col0 + row) * K + kk + scol);
            *(us4*)&Bsl[row][((sslot ^ (row & 7)) << 3) + (shalf << 2)] = bv;
        }
        __syncthreads();
        #pragma unroll
        for (int k2 = 0; k2 < 2; ++k2) {
            short8 af[2], bfr[2];
            #pragma unroll
            for (int m = 0; m < 2; ++m) {
                int rowA = wr * 32 + m * 16 + lrow;
                af[m] = *(short8*)&Asl[rowA][((k2 * 4 + lk) ^ (rowA & 7)) << 3];
                int rowB = wc * 32 + m * 16 + lrow;
                bfr[m] = *(short8*)&Bsl[rowB][((k2 * 4 + lk) ^ (rowB & 7)) << 3];
            }
            #pragma unroll
            for (int m = 0; m < 2; ++m)
                #pragma unroll
                for (int n = 0; n < 2; ++n)
                    acc[m][n] = __builtin_amdgcn_mfma_f32_16x16x32_bf16(af[m], bfr[n], acc[m][n], 0, 0, 0);
        }
        __syncthreads();
    }
    #pragma unroll
    for (int m = 0; m < 2; ++m) {
        #pragma unroll
        for (int n = 0; n < 2; ++n) {
            int col = col0 + wc * 32 + n * 16 + lrow;
            #pragma unroll
            for (int j = 0; j < 4; ++j) {
                int r = row0 + wr * 32 + m * 16 + lk * 4 + j;
                size_t cp = ((size_t)(r / crpb) * cbsr + coff + (r % crpb)) * (size_t)N + col;
                float o = acc[m][n][j];
                if (BIAS)   o += bias[col];
                if (DOGELU) o = gelu_f(o);
                if (RES)    o += Res[cp];
                C[cp] = o;
            }
        }
    }
}

// ---------------- f32 tiled GEMM (tiny M=64 glob cases) ----------------
template<int BIAS, int DOGELU, int RES>
__global__ __launch_bounds__(256) void gemm_k(
    const float* __restrict__ A, const float* __restrict__ Bm,
    const float* __restrict__ bias, const float* __restrict__ Res,
    float* __restrict__ C, int M, int N, int K,
    int arpb, int absr, int aoff, int crpb, int cbsr, int coff)
{
    __shared__ float As[16][68];
    __shared__ float Bs[16][64];
    int t = threadIdx.x;
    int col0 = blockIdx.x * 64, row0 = blockIdx.y * 64;
    int tx = t & 15, ty = t >> 4;
    int la_r = t >> 2, la_c = (t & 3) << 2;
    int ar = row0 + la_r;
    size_t a_base = ((size_t)(ar / arpb) * absr + aoff + (ar % arpb)) * (size_t)K;
    float acc[4][4] = {};
    for (int kk = 0; kk < K; kk += 16) {
        float4 av = *(const float4*)(A + a_base + kk + la_c);
        float4 bv = *(const float4*)(Bm + (size_t)(kk + ty) * N + col0 + (tx << 2));
        As[la_c + 0][la_r] = av.x;
        As[la_c + 1][la_r] = av.y;
        As[la_c + 2][la_r] = av.z;
        As[la_c + 3][la_r] = av.w;
        *(float4*)&Bs[ty][tx << 2] = bv;
        __syncthreads();
        #pragma unroll
        for (int k = 0; k < 16; ++k) {
            float4 a = *(float4*)&As[k][ty << 2];
            float4 b = *(float4*)&Bs[k][tx << 2];
            acc[0][0] += a.x * b.x; acc[0][1] += a.x * b.y; acc[0][2] += a.x * b.z; acc[0][3] += a.x * b.w;
            acc[1][0] += a.y * b.x; acc[1][1] += a.y * b.y; acc[1][2] += a.y * b.z; acc[1][3] += a.y * b.w;
            acc[2][0] += a.z * b.x; acc[2][1] += a.z * b.y; acc[2][2] += a.z * b.z; acc[2][3] += a.z * b.w;
            acc[3][0] += a.w * b.x; acc[3][1] += a.w * b.y; acc[3][2] += a.w * b.z; acc[3][3] += a.w * b.w;
        }
        __syncthreads();
    }
    #pragma unroll
    for (int i = 0; i < 4; ++i) {
        int r = row0 + (ty << 2) + i;
        size_t cp = ((size_t)(r / crpb) * cbsr + coff + (r % crpb)) * (size_t)N + col0 + (tx << 2);
        #pragma unroll
        for (int j = 0; j < 4; ++j) {
            float o = acc[i][j];
            if (BIAS)   o += bias[col0 + (tx << 2) + j];
            if (DOGELU) o = gelu_f(o);
            if (RES)    o += Res[cp + j];
            C[cp + j] = o;
        }
    }
}

// ---------------- fused spatial attention, two-pass register softmax ----------------
// One block per (b,l), t = (h=t>>5, d=t&31). Butterfly leaves the score in ALL
// lanes, so each thread keeps all 49 scores in registers -> softmax with zero
// shuffles/LDS. Pass B is 49 independent load+FMA. qw/epilogue projections via
// LDS broadcast (no shuffles).
__global__ __launch_bounds__(256) void attn_sp_k(
    const float* __restrict__ QKV, const float* __restrict__ KVGL,
    const int* __restrict__ idx, const float* __restrict__ rpe,
    const float* __restrict__ srpe, const float* __restrict__ dist,
    const float* __restrict__ wkpe, const float* __restrict__ wvpe,
    const float* __restrict__ lsig, const float* __restrict__ gbias,
    float* __restrict__ O)
{
    __shared__ float s_rpe[17 * 32];
    __shared__ float s_q[256];      // reused later as racc stage
    __shared__ float s_d[16];
    __shared__ int   s_row[17];
    int t = threadIdx.x;
    int r = blockIdx.x;          // b*LS + l
    int h = t >> 5, d = t & 31;
    int b = r >> 11;

    if (t < 32) s_rpe[t] = srpe[(size_t)r * 32 + t];
    for (int i = t; i < 512; i += 256) s_rpe[32 + i] = rpe[(size_t)r * 512 + i];
    if (t < 16) {
        s_row[t + 1] = (b << 11) + idx[r * 16 + t];
        s_d[t] = dist[(size_t)r * 16 + t];
    }
    if (t == 16) s_row[0] = r;
    float qt = QKV[(size_t)r * 768 + t];
    s_q[t] = qt;
    __syncthreads();

    // qw[p=d] = sum_{d'} q[h,d'] * Wkpe[p][h*32+d']   (LDS broadcast dot)
    float qw = 0.0f;
    {
        const float* wkh = wkpe + d * 256 + h * 32;
        const float* sqh = s_q + h * 32;
        #pragma unroll
        for (int p = 0; p < 32; ++p) qw += sqh[p] * wkh[p];
    }
    float inv2s = 1.0f / (2.0f * __expf(2.0f * lsig[h]));
    float gb = gbias[0];
    float qs = qt * SCALE, qws = qw * SCALE;

    float sc[NCTX];
    // pass A: scores (independent butterflies, compiler pipelines)
    #pragma unroll
    for (int c = 0; c < 17; ++c) {
        int row = s_row[c];
        float kt = QKV[(size_t)row * 768 + 256 + t];
        float part = qs * kt + s_rpe[c * 32 + d] * qws;
        part += __shfl_xor(part, 16); part += __shfl_xor(part, 8);
        part += __shfl_xor(part, 4);  part += __shfl_xor(part, 2);
        part += __shfl_xor(part, 1);
        sc[c] = part;
    }
    #pragma unroll
    for (int c = 0; c < NG; ++c) {
        float kt = KVGL[(size_t)(b * NG + c) * 512 + t];
        float part = qs * kt;
        part += __shfl_xor(part, 16); part += __shfl_xor(part, 8);
        part += __shfl_xor(part, 4);  part += __shfl_xor(part, 2);
        part += __shfl_xor(part, 1);
        sc[17 + c] = part;
    }

    // bias + softmax entirely in registers
    #pragma unroll
    for (int c = 1; c < 17; ++c) { float dd = s_d[c - 1]; sc[c] -= dd * dd * inv2s; }
    #pragma unroll
    for (int c = 17; c < NCTX; ++c) sc[c] += gb;
    float mx = sc[0];
    #pragma unroll
    for (int c = 1; c < NCTX; ++c) mx = fmaxf(mx, sc[c]);
    float sum = 0.0f;
    #pragma unroll
    for (int c = 0; c < NCTX; ++c) { float e = __expf(sc[c] - mx); sc[c] = e; sum += e; }
    float inv = 1.0f / sum;

    // pass B: weighted V (independent loads)
    float acc = 0.0f, racc = 0.0f;
    #pragma unroll
    for (int c = 0; c < 17; ++c) {
        int row = s_row[c];
        acc  += sc[c] * QKV[(size_t)row * 768 + 512 + t];
        racc += sc[c] * s_rpe[c * 32 + d];
    }
    #pragma unroll
    for (int c = 0; c < NG; ++c)
        acc += sc[17 + c] * KVGL[(size_t)(b * NG + c) * 512 + 256 + t];

    // rpe-V projection via LDS broadcast
    __syncthreads();
    s_q[t] = racc;
    __syncthreads();
    {
        const float* srh = s_q + h * 32;
        #pragma unroll
        for (int p = 0; p < 32; ++p) acc += srh[p] * wvpe[p * 256 + t];
    }
    O[(size_t)r * 256 + t] = acc * inv;
}

// ---------------- global attention: scores ----------------
__global__ __launch_bounds__(256) void ga_scores_k(
    const float* __restrict__ QG, const float* __restrict__ KVG, float* __restrict__ A2)
{
    int t = threadIdx.x;
    int blk = blockIdx.x;           // b*2080 + c
    int b = blk / ROWS_B;
    int h = t >> 5, d = t & 31;
    float kt = KVG[(size_t)blk * 512 + t];
    for (int g = 0; g < NG; ++g) {
        float ps = QG[((size_t)(b * NG + g)) * 256 + t] * kt;
        ps += __shfl_xor(ps, 16); ps += __shfl_xor(ps, 8); ps += __shfl_xor(ps, 4);
        ps += __shfl_xor(ps, 2);  ps += __shfl_xor(ps, 1);
        if (d == 0) A2[((size_t)(b * NH + h) * NG + g) * ROWS_B + (blk % ROWS_B)] = ps * SCALE;
    }
}

// ---------------- global attention: row softmax over 2080 ----------------
__global__ __launch_bounds__(256) void ga_softmax_k(float* __restrict__ A2)
{
    __shared__ float red[8];
    int t = threadIdx.x;
    float* row = A2 + (size_t)blockIdx.x * ROWS_B;
    float lm = -1e30f;
    for (int i = t; i < ROWS_B; i += 256) lm = fmaxf(lm, row[i]);
    #pragma unroll
    for (int m = 32; m >= 1; m >>= 1) lm = fmaxf(lm, __shfl_xor(lm, m));
    if ((t & 63) == 0) red[t >> 6] = lm;
    __syncthreads();
    float M = fmaxf(fmaxf(red[0], red[1]), fmaxf(red[2], red[3]));
    float ls = 0.0f;
    for (int i = t; i < ROWS_B; i += 256) {
        float e = __expf(row[i] - M);
        row[i] = e;
        ls += e;
    }
    #pragma unroll
    for (int m = 32; m >= 1; m >>= 1) ls += __shfl_xor(ls, m);
    if ((t & 63) == 0) red[4 + (t >> 6)] = ls;
    __syncthreads();
    float inv = 1.0f / (red[4] + red[5] + red[6] + red[7]);
    for (int i = t; i < ROWS_B; i += 256) row[i] *= inv;
}

// ---------------- global attention: weighted V (split-K) ----------------
__global__ __launch_bounds__(256) void ga_wv_k(
    const float* __restrict__ A2, const float* __restrict__ KVG, float* __restrict__ OGP)
{
    int t = threadIdx.x;
    int bg = blockIdx.x;       // b*32+g
    int s = blockIdx.y;        // 0..7
    int b = bg >> 5, g = bg & 31;
    int h = t >> 5;
    const float* w = A2 + ((size_t)(b * NH + h) * NG + g) * ROWS_B;
    const float* v = KVG + (size_t)b * ROWS_B * 512 + 256;
    float acc = 0.0f;
    int c0 = s * 260, c1 = c0 + 260;
    for (int c = c0; c < c1; ++c) acc += w[c] * v[(size_t)c * 512 + t];
    OGP[((size_t)bg * 8 + s) * 256 + t] = acc;
}

__global__ __launch_bounds__(256) void ga_red_k(
    const float* __restrict__ OGP, float* __restrict__ OG)
{
    int t = threadIdx.x, bg = blockIdx.x;
    float a = 0.0f;
    #pragma unroll
    for (int s = 0; s < 8; ++s) a += OGP[((size_t)bg * 8 + s) * 256 + t];
    OG[(size_t)bg * 256 + t] = a;
}

// ---------------- launch ----------------
extern "C" void kernel_launch(void* const* d_in, const int* in_sizes, int n_in,
                              void* d_out, int out_size, void* d_ws, size_t ws_size,
                              hipStream_t stream)
{
    const float* latents = (const float*)d_in[0];
    const int*   idx     = (const int*)d_in[1];
    const float* rpe     = (const float*)d_in[2];
    const float* srpe    = (const float*)d_in[3];
    const float* dist    = (const float*)d_in[4];
    const float* sa_wq   = (const float*)d_in[6];
    const float* sa_wk   = (const float*)d_in[7];
    const float* sa_wv   = (const float*)d_in[8];
    const float* sa_wo   = (const float*)d_in[9];
    const float* sa_bo   = (const float*)d_in[10];
    const float* lsig    = (const float*)d_in[11];
    const float* gbias   = (const float*)d_in[12];
    const float* ln1g    = (const float*)d_in[13];
    const float* ln1b    = (const float*)d_in[14];
    const float* ln2g    = (const float*)d_in[15];
    const float* ln2b    = (const float*)d_in[16];
    const float* sff_w1  = (const float*)d_in[17];
    const float* sff_b1  = (const float*)d_in[18];
    const float* sff_w2  = (const float*)d_in[19];
    const float* sff_b2  = (const float*)d_in[20];
    const float* ga_wq   = (const float*)d_in[21];
    const float* ga_wk   = (const float*)d_in[22];
    const float* ga_wv   = (const float*)d_in[23];
    const float* ga_wo   = (const float*)d_in[24];
    const float* ga_bo   = (const float*)d_in[25];
    const float* ln3g    = (const float*)d_in[27];
    const float* ln3b    = (const float*)d_in[28];
    const float* ln4g    = (const float*)d_in[29];
    const float* ln4b    = (const float*)d_in[30];
    const float* gff_w1  = (const float*)d_in[31];
    const float* gff_b1  = (const float*)d_in[32];
    const float* gff_w2  = (const float*)d_in[33];
    const float* gff_b2  = (const float*)d_in[34];
    float* out = (float*)d_out;

    const size_t SZ = (size_t)4096 * 256;             // 1,048,576
    float* ws   = (float*)d_ws;
    float* X    = ws;                                  // [0, SZ)
    float* QKV  = ws + SZ;                             // [SZ, 4SZ)  rows x 768
    float* O    = ws + 4 * SZ;                         // [4SZ, 5SZ)
    float* H1   = ws + SZ;                             // overlays QKV+O after attn/wo
    float* KVG  = ws + SZ;                             // overlays H1 after ff2; [2*2080][512]
    float* KVGL = ws + 5 * SZ;                         // [64][512]
    float* GQ   = KVGL + 32768;
    float* QG   = GQ + 16384;
    float* OG   = QG + 16384;
    float* GLN  = OG + 16384;
    float* GH   = GLN + 16384;                         // [64][1024]
    float* A2   = GH + 65536;                          // [2*8*32][2080]
    float* OGP  = A2 + (size_t)2 * NH * NG * ROWS_B;   // [64*8][256]

    // bf16 transposed weights overlay A2 (scores writes A2 after last wt read)
    unsigned short* wt = (unsigned short*)A2;
    unsigned short* wt_qkv = wt;                 // saq|sak|sav  [768][256]
    unsigned short* wt_sak = wt + 65536;         // (with sav: [512][256])
    unsigned short* wt_sao = wt + 196608;
    unsigned short* wt_ff1 = wt + 262144;        // [1024][256]
    unsigned short* wt_ff2 = wt + 524288;        // [256][1024]
    unsigned short* wt_gakv = wt + 786432;       // gak|gav [512][256]
    unsigned short* wt_gaq = wt + 917504;

    dim3 blk(256);
    const float* wkpe = sa_wk + 256 * 256;
    const float* wvpe = sa_wv + 256 * 256;

    // batched weight prep: 240 tiles
    WTab tab;
    tab.e[0] = { sa_wq,  wt_qkv,        256,  256,   0 };
    tab.e[1] = { sa_wk,  wt + 65536,    256,  256,  16 };
    tab.e[2] = { sa_wv,  wt + 131072,   256,  256,  32 };
    tab.e[3] = { sa_wo,  wt_sao,        256,  256,  48 };
    tab.e[4] = { sff_w1, wt_ff1,        256, 1024,  64 };
    tab.e[5] = { sff_w2, wt_ff2,       1024,  256, 128 };
    tab.e[6] = { ga_wk,  wt + 786432,   256,  256, 192 };
    tab.e[7] = { ga_wv,  wt + 851968,   256,  256, 208 };
    tab.e[8] = { ga_wq,  wt_gaq,        256,  256, 224 };
    wconv_all_k<<<dim3(240), blk, 0, stream>>>(tab);

    // LN1 (spatial) and LN3 (glob)
    ln_rows_k<<<dim3(4096), blk, 0, stream>>>(latents, ln1g, ln1b, X, LS, ROWS_B, 0, LS, LS, 0);
    ln_rows_k<<<dim3(64),   blk, 0, stream>>>(latents, ln3g, ln3b, GQ, NG, ROWS_B, LS, NG, NG, 0);

    // fused QKV projection (N=768) and glob K|V (N=512, raw latents)
    mgemm_k<0,0,0><<<dim3(12,64), blk, 0, stream>>>(X, wt_qkv, nullptr, nullptr, QKV, 4096,768,256, 4096,4096,0, 4096,4096,0);
    mgemm_k<0,0,0><<<dim3(8,1),  blk, 0, stream>>>(latents, wt_sak, nullptr, nullptr, KVGL, 64,512,256, 32,ROWS_B,LS, 64,64,0);

    // fused spatial attention -> O
    attn_sp_k<<<dim3(4096), blk, 0, stream>>>(QKV, KVGL, idx, rpe, srpe, dist,
                                              wkpe, wvpe, lsig, gbias, O);

    // spatial residual: d_out[:, :LS] = latents + O@wo + bo
    mgemm_k<1,0,1><<<dim3(4,64), blk, 0, stream>>>(O, wt_sao, sa_bo, latents, out, 4096,256,256, 4096,4096,0, LS,ROWS_B,0);

    // spatial FF
    ln_rows_k<<<dim3(4096), blk, 0, stream>>>(out, ln2g, ln2b, X, LS, ROWS_B, 0, LS, LS, 0);
    mgemm_k<1,1,0><<<dim3(16,64), blk, 0, stream>>>(X, wt_ff1, sff_b1, nullptr, H1, 4096,1024,256, 4096,4096,0, 4096,4096,0);
    mgemm_k<1,0,1><<<dim3(4,64),  blk, 0, stream>>>(H1, wt_ff2, sff_b2, out, out, 4096,256,1024, 4096,4096,0, LS,ROWS_B,0);

    // global attention projections: KVG rows = [spatial_new ; gq_in] per batch
    mgemm_k<0,0,0><<<dim3(8,64), blk, 0, stream>>>(out, wt_gakv, nullptr, nullptr, KVG, 4096,512,256, LS,ROWS_B,0, LS,ROWS_B,0);
    mgemm_k<0,0,0><<<dim3(8,1),  blk, 0, stream>>>(GQ,  wt_gakv, nullptr, nullptr, KVG, 64,512,256, 64,64,0, NG,ROWS_B,LS);
    mgemm_k<0,0,0><<<dim3(4,1),  blk, 0, stream>>>(GQ,  wt_gaq, nullptr, nullptr, QG, 64,256,256, 64,64,0, 64,64,0);

    ga_scores_k<<<dim3(2 * ROWS_B), blk, 0, stream>>>(QG, KVG, A2);
    ga_softmax_k<<<dim3(512), blk, 0, stream>>>(A2);
    ga_wv_k<<<dim3(64, 8), blk, 0, stream>>>(A2, KVG, OGP);
    ga_red_k<<<dim3(64), blk, 0, stream>>>(OGP, OG);

    // glob residual + FF (tiny, f32)
    gemm_k<1,0,1><<<dim3(4,1), blk, 0, stream>>>(OG, ga_wo, ga_bo, latents, out, 64,256,256, 64,64,0, NG,ROWS_B,LS);
    ln_rows_k<<<dim3(64), blk, 0, stream>>>(out, ln4g, ln4b, GLN, NG, ROWS_B, LS, NG, NG, 0);
    gemm_k<1,1,0><<<dim3(16,1), blk, 0, stream>>>(GLN, gff_w1, gff_b1, nullptr, GH, 64,1024,256, 64,64,0, 64,64,0);
    gemm_k<1,0,1><<<dim3(4,1),  blk, 0, stream>>>(GH, gff_w2, gff_b2, out, out, 64,256,1024, 64,64,0, NG,ROWS_B,LS);
}

// Round 5
// 305.311 us; speedup vs baseline: 2.0963x; 1.1836x over previous
//
#include <hip/hip_runtime.h>
#include <math.h>

// B=2, LS=2048, G=32, KNN=16, DIM=256, PE=32, H=8, DH=32, INNER=256, FF=1024
#define LS 2048
#define NG 32
#define ROWS_B 2080
#define DIM 256
#define PE 32
#define NH 8
#define DH 32
#define NCTX 49
#define SCALE 0.17677669529663687f  // 1/sqrt(32)

typedef __attribute__((ext_vector_type(8))) short short8;
typedef __attribute__((ext_vector_type(4))) float f32x4;
typedef __attribute__((ext_vector_type(4))) unsigned short us4;

__device__ __forceinline__ unsigned short f2bf(float x)
{
    unsigned int u = __float_as_uint(x);
    unsigned int r = (u + 0x7fffu + ((u >> 16) & 1u)) >> 16;
    return (unsigned short)r;
}
__device__ __forceinline__ float bf2f(unsigned short v)
{
    return __uint_as_float((unsigned int)v << 16);
}
__device__ __forceinline__ float4 bf2f4(us4 v)
{
    return (float4){ bf2f(v.x), bf2f(v.y), bf2f(v.z), bf2f(v.w) };
}
__device__ __forceinline__ float dot4(float4 a, float4 b)
{
    return a.x * b.x + a.y * b.y + a.z * b.z + a.w * b.w;
}
__device__ __forceinline__ float gelu_f(float x)
{
    float x3 = x * x * x;
    return 0.5f * x * (1.0f + tanhf(0.7978845608028654f * (x + 0.044715f * x3)));
}

// ---------------- fused LN1 (spatial, 4096 rows) + LN3 (glob, 64 rows) ----------------
__global__ __launch_bounds__(256) void ln_dual_k(
    const float* __restrict__ latents,
    const float* __restrict__ g1, const float* __restrict__ b1,
    const float* __restrict__ g3, const float* __restrict__ b3,
    float* __restrict__ X, float* __restrict__ GQ)
{
    __shared__ float red[8];
    int blk = blockIdx.x, t = threadIdx.x;
    const float* gam; const float* bet; size_t ip; float* op;
    if (blk < 4096) {
        int b = blk >> 11;
        ip = ((size_t)b * ROWS_B + (blk & 2047)) * DIM + t;
        op = X + (size_t)blk * DIM + t;
        gam = g1; bet = b1;
    } else {
        int r2 = blk - 4096;
        int b = r2 >> 5;
        ip = ((size_t)b * ROWS_B + LS + (r2 & 31)) * DIM + t;
        op = GQ + (size_t)r2 * DIM + t;
        gam = g3; bet = b3;
    }
    float v = latents[ip];
    float a = v, b2 = v * v;
    #pragma unroll
    for (int m = 32; m >= 1; m >>= 1) { a += __shfl_xor(a, m); b2 += __shfl_xor(b2, m); }
    if ((t & 63) == 0) { red[t >> 6] = a; red[4 + (t >> 6)] = b2; }
    __syncthreads();
    float mean = (red[0] + red[1] + red[2] + red[3]) * (1.0f / 256.0f);
    float var  = (red[4] + red[5] + red[6] + red[7]) * (1.0f / 256.0f) - mean * mean;
    *op = (v - mean) * rsqrtf(var + 1e-5f) * gam[t] + bet[t];
}

// ---------------- plain LN (ln2) ----------------
__global__ __launch_bounds__(256) void ln_rows_k(
    const float* __restrict__ in, const float* __restrict__ gam,
    const float* __restrict__ bet, float* __restrict__ out)
{
    __shared__ float red[8];
    int r = blockIdx.x, t = threadIdx.x;
    int b = r >> 11;
    size_t ip = ((size_t)b * ROWS_B + (r & 2047)) * DIM + t;
    float v = in[ip];
    float a = v, b2 = v * v;
    #pragma unroll
    for (int m = 32; m >= 1; m >>= 1) { a += __shfl_xor(a, m); b2 += __shfl_xor(b2, m); }
    if ((t & 63) == 0) { red[t >> 6] = a; red[4 + (t >> 6)] = b2; }
    __syncthreads();
    float mean = (red[0] + red[1] + red[2] + red[3]) * (1.0f / 256.0f);
    float var  = (red[4] + red[5] + red[6] + red[7]) * (1.0f / 256.0f) - mean * mean;
    out[(size_t)r * DIM + t] = (v - mean) * rsqrtf(var + 1e-5f) * gam[t] + bet[t];
}

// ---------------- batched weight transpose+convert (bf16, [n][k]) ----------------
struct WEnt { const float* src; unsigned short* dst; int K; int N; int t0; };
struct WTab { WEnt e[9]; };

__global__ __launch_bounds__(256) void wconv_all_k(WTab tab)
{
    __shared__ unsigned short tile[64][72];
    int blk = blockIdx.x;
    int i = 0;
    #pragma unroll
    for (int j = 1; j < 9; ++j) if (blk >= tab.e[j].t0) i = j;
    const float* W = tab.e[i].src;
    unsigned short* Wt = tab.e[i].dst;
    int K = tab.e[i].K, N = tab.e[i].N;
    int local = blk - tab.e[i].t0;
    int nb = N >> 6;
    int n0 = (local % nb) * 64, k0 = (local / nb) * 64;
    int t = threadIdx.x;
    #pragma unroll
    for (int r = 0; r < 4; ++r) {
        int k = r * 16 + (t >> 4);
        int n = (t & 15) * 4;
        float4 wv = *(const float4*)(W + (size_t)(k0 + k) * N + n0 + n);
        tile[k][n + 0] = f2bf(wv.x);
        tile[k][n + 1] = f2bf(wv.y);
        tile[k][n + 2] = f2bf(wv.z);
        tile[k][n + 3] = f2bf(wv.w);
    }
    __syncthreads();
    #pragma unroll
    for (int r = 0; r < 4; ++r) {
        int n = r * 16 + (t >> 4);
        int k = (t & 15) * 4;
        us4 o;
        o.x = tile[k + 0][n];
        o.y = tile[k + 1][n];
        o.z = tile[k + 2][n];
        o.w = tile[k + 3][n];
        *(us4*)(Wt + (size_t)(n0 + n) * K + k0 + k) = o;
    }
}

// ---------------- special folded weights: Wqw (qw cols of QKV weight) and Wo2=[Wo;Wvo] ----
// blk<256: col j of qw section: wt_qkvw[(768+j)][k] = sum_dd Wq[k][h*32+dd]*Wkpe[p][h*32+dd]
// blk>=256: row n of wo2: wt_wo2[n][k] ; k<256 -> Wo[k][n]; k=256+j -> sum_dd Wvpe[p][..]*Wo[..][n]
__global__ __launch_bounds__(256) void wspecial_k(
    const float* __restrict__ sa_wq, const float* __restrict__ sa_wk,
    const float* __restrict__ sa_wv, const float* __restrict__ sa_wo,
    unsigned short* __restrict__ wt_qkvw, unsigned short* __restrict__ wt_wo2)
{
    const float* wkpe = sa_wk + 256 * 256;
    const float* wvpe = sa_wv + 256 * 256;
    int blk = blockIdx.x, t = threadIdx.x;
    if (blk < 256) {
        int j = blk, h = j >> 5, p = j & 31;
        const float* wq = sa_wq + (size_t)t * 256 + h * 32;
        const float* wk = wkpe + (size_t)p * 256 + h * 32;
        float acc = 0.0f;
        #pragma unroll
        for (int dd = 0; dd < 32; ++dd) acc += wq[dd] * wk[dd];
        wt_qkvw[(size_t)(768 + j) * 256 + t] = f2bf(acc);
    } else {
        int n = blk - 256;
        #pragma unroll
        for (int kk = 0; kk < 2; ++kk) {
            int k = t + kk * 256;
            float v;
            if (k < 256) v = sa_wo[(size_t)k * 256 + n];
            else {
                int j = k - 256, h = j >> 5, p = j & 31;
                float a = 0.0f;
                #pragma unroll
                for (int dd = 0; dd < 32; ++dd)
                    a += wvpe[(size_t)p * 256 + h * 32 + dd] * sa_wo[(size_t)(h * 32 + dd) * 256 + n];
                v = a;
            }
            wt_wo2[(size_t)n * 512 + k] = f2bf(v);
        }
    }
}

// ---------------- bf16 MFMA GEMM ----------------
// 64x64x64 tiles, 4 waves (2x2 quadrants of 32x32), 16x16x32 bf16 MFMA.
// A: f32 (converted) or bf16. Bt: bf16 [N][bstr] K-contiguous. C: f32 or bf16.
template<int BIAS, int DOGELU, int RES, int ABF16, int CBF16>
__global__ __launch_bounds__(256) void mgemm_k(
    const void* __restrict__ Av, const unsigned short* __restrict__ Bt,
    const float* __restrict__ bias, const float* __restrict__ Res,
    void* __restrict__ Cv, int M, int N, int K, int bstr,
    int arpb, int absr, int aoff, int crpb, int cbsr, int coff)
{
    __shared__ unsigned short Asl[64][64];
    __shared__ unsigned short Bsl[64][64];
    int t = threadIdx.x;
    int col0 = blockIdx.x * 64, row0 = blockIdx.y * 64;
    int lane = t & 63, w = t >> 6;
    int wr = w >> 1, wc = w & 1;
    int lrow = lane & 15, lk = lane >> 4;

    int srow = t >> 4;
    int scol = (t & 15) << 2;
    int sslot = (t & 15) >> 1;
    int shalf = (t & 15) & 1;

    f32x4 acc[2][2];
    #pragma unroll
    for (int m = 0; m < 2; ++m)
        #pragma unroll
        for (int n = 0; n < 2; ++n)
            acc[m][n] = (f32x4){0.f, 0.f, 0.f, 0.f};

    for (int kk = 0; kk < K; kk += 64) {
        #pragma unroll
        for (int r = 0; r < 4; ++r) {
            int row = r * 16 + srow;
            int ar = row0 + row;
            size_t ab = ((size_t)(ar / arpb) * absr + aoff + (ar % arpb)) * (size_t)K + kk + scol;
            us4 ap;
            if (ABF16) {
                ap = *(const us4*)((const unsigned short*)Av + ab);
            } else {
                float4 av = *(const float4*)((const float*)Av + ab);
                ap.x = f2bf(av.x); ap.y = f2bf(av.y); ap.z = f2bf(av.z); ap.w = f2bf(av.w);
            }
            *(us4*)&Asl[row][((sslot ^ (row & 7)) << 3) + (shalf << 2)] = ap;
            us4 bv = *(const us4*)(Bt + (size_t)(col0 + row) * bstr + kk + scol);
            *(us4*)&Bsl[row][((sslot ^ (row & 7)) << 3) + (shalf << 2)] = bv;
        }
        __syncthreads();
        #pragma unroll
        for (int k2 = 0; k2 < 2; ++k2) {
            short8 af[2], bfr[2];
            #pragma unroll
            for (int m = 0; m < 2; ++m) {
                int rowA = wr * 32 + m * 16 + lrow;
                af[m] = *(short8*)&Asl[rowA][((k2 * 4 + lk) ^ (rowA & 7)) << 3];
                int rowB = wc * 32 + m * 16 + lrow;
                bfr[m] = *(short8*)&Bsl[rowB][((k2 * 4 + lk) ^ (rowB & 7)) << 3];
            }
            #pragma unroll
            for (int m = 0; m < 2; ++m)
                #pragma unroll
                for (int n = 0; n < 2; ++n)
                    acc[m][n] = __builtin_amdgcn_mfma_f32_16x16x32_bf16(af[m], bfr[n], acc[m][n], 0, 0, 0);
        }
        __syncthreads();
    }
    #pragma unroll
    for (int m = 0; m < 2; ++m) {
        #pragma unroll
        for (int n = 0; n < 2; ++n) {
            int col = col0 + wc * 32 + n * 16 + lrow;
            #pragma unroll
            for (int j = 0; j < 4; ++j) {
                int r = row0 + wr * 32 + m * 16 + lk * 4 + j;
                size_t cp = ((size_t)(r / crpb) * cbsr + coff + (r % crpb)) * (size_t)N + col;
                float o = acc[m][n][j];
                if (BIAS)   o += bias[col];
                if (DOGELU) o = gelu_f(o);
                if (RES)    o += Res[cp];
                if (CBF16) ((unsigned short*)Cv)[cp] = f2bf(o);
                else       ((float*)Cv)[cp] = o;
            }
        }
    }
}

// ---------------- fused spatial attention ----------------
// Block per (b,l); 4 waves; lane = h*8+do, thread covers elems h*32+do*4..+3.
// Contexts strided across waves (c = w,w+4,...). Scores need only a 3-step
// 8-lane butterfly. qw (score rpe-term) is precomputed as QKV cols 768..1023;
// the V rpe-term (racc) is emitted as R and folded into the Wo GEMM (Wvo).
__global__ __launch_bounds__(256) void attn_sp_k(
    const unsigned short* __restrict__ QKV, const float* __restrict__ KVGL,
    const int* __restrict__ idx, const float* __restrict__ rpe,
    const float* __restrict__ srpe, const float* __restrict__ dist,
    const float* __restrict__ lsig, const float* __restrict__ gbias,
    float* __restrict__ OR)
{
    __shared__ float s_rpe[17 * 32];
    __shared__ float s_sc[NCTX * 8];
    __shared__ float s_red[32 * 64];
    __shared__ float s_d[16];
    __shared__ int   s_row[17];
    int t = threadIdx.x;
    int r = blockIdx.x;
    int b = r >> 11;
    int w = t >> 6, lane = t & 63;
    int h = lane >> 3, dg = lane & 7;

    if (t < 32) s_rpe[t] = srpe[(size_t)r * 32 + t];
    for (int i = t; i < 512; i += 256) s_rpe[32 + i] = rpe[(size_t)r * 512 + i];
    if (t < 16) {
        s_row[t + 1] = (b << 11) + idx[r * 16 + t];
        s_d[t] = dist[(size_t)r * 16 + t];
    }
    if (t == 16) s_row[0] = r;

    size_t qb = (size_t)r * 1024 + lane * 4;
    float4 q4  = bf2f4(*(const us4*)(QKV + qb));
    float4 qw4 = bf2f4(*(const us4*)(QKV + qb + 768));
    float inv2s = 1.0f / (2.0f * __expf(2.0f * lsig[h]));
    float gb = gbias[0];
    __syncthreads();

    float sc_reg[13];
    #pragma unroll
    for (int i = 0; i < 13; ++i) {
        int c = w + 4 * i;
        if (c < NCTX) {
            float part, bia;
            if (c < 17) {
                int row = s_row[c];
                float4 k4 = bf2f4(*(const us4*)(QKV + (size_t)row * 1024 + 256 + lane * 4));
                float4 rv4 = *(const float4*)&s_rpe[c * 32 + dg * 4];
                part = dot4(q4, k4) + dot4(rv4, qw4);
                bia = (c == 0) ? 0.0f : -s_d[c - 1] * s_d[c - 1] * inv2s;
            } else {
                float4 k4 = *(const float4*)(KVGL + ((size_t)(b * NG + (c - 17))) * 512 + lane * 4);
                part = dot4(q4, k4);
                bia = gb;
            }
            part += __shfl_xor(part, 1);
            part += __shfl_xor(part, 2);
            part += __shfl_xor(part, 4);
            float sval = part * SCALE + bia;
            if (dg == 0) s_sc[c * 8 + h] = sval;
            sc_reg[i] = sval;
        }
    }
    __syncthreads();

    // cooperative softmax stats over the 49 staged scores (8 lanes per h)
    float vals[7];
    float lm = -3.0e38f;
    #pragma unroll
    for (int i = 0; i < 7; ++i) {
        int cc = dg + 8 * i;
        if (cc < NCTX) { float v = s_sc[cc * 8 + h]; vals[i] = v; lm = fmaxf(lm, v); }
    }
    lm = fmaxf(lm, __shfl_xor(lm, 1));
    lm = fmaxf(lm, __shfl_xor(lm, 2));
    lm = fmaxf(lm, __shfl_xor(lm, 4));
    float ls = 0.0f;
    #pragma unroll
    for (int i = 0; i < 7; ++i) {
        int cc = dg + 8 * i;
        if (cc < NCTX) ls += __expf(vals[i] - lm);
    }
    ls += __shfl_xor(ls, 1);
    ls += __shfl_xor(ls, 2);
    ls += __shfl_xor(ls, 4);
    float inv = 1.0f / ls;

    // pass B: weighted V (+rpe accumulation)
    float4 acc4 = (float4){0, 0, 0, 0}, racc4 = (float4){0, 0, 0, 0};
    #pragma unroll
    for (int i = 0; i < 13; ++i) {
        int c = w + 4 * i;
        if (c < NCTX) {
            float p = __expf(sc_reg[i] - lm);
            float4 v4;
            if (c < 17) {
                int row = s_row[c];
                v4 = bf2f4(*(const us4*)(QKV + (size_t)row * 1024 + 512 + lane * 4));
                float4 rv4 = *(const float4*)&s_rpe[c * 32 + dg * 4];
                racc4.x += p * rv4.x; racc4.y += p * rv4.y;
                racc4.z += p * rv4.z; racc4.w += p * rv4.w;
            } else {
                v4 = *(const float4*)(KVGL + ((size_t)(b * NG + (c - 17))) * 512 + 256 + lane * 4);
            }
            acc4.x += p * v4.x; acc4.y += p * v4.y;
            acc4.z += p * v4.z; acc4.w += p * v4.w;
        }
    }
    // cross-wave reduce: component-sliced, conflict-free
    s_red[(w * 8 + 0) * 64 + lane] = acc4.x;
    s_red[(w * 8 + 1) * 64 + lane] = acc4.y;
    s_red[(w * 8 + 2) * 64 + lane] = acc4.z;
    s_red[(w * 8 + 3) * 64 + lane] = acc4.w;
    s_red[(w * 8 + 4) * 64 + lane] = racc4.x;
    s_red[(w * 8 + 5) * 64 + lane] = racc4.y;
    s_red[(w * 8 + 6) * 64 + lane] = racc4.z;
    s_red[(w * 8 + 7) * 64 + lane] = racc4.w;
    __syncthreads();
    // thread (w, lane) finalizes element e = h*32 + dg*4 + w at position lane
    {
        int j = w;
        float a = 0.0f, rr = 0.0f;
        #pragma unroll
        for (int ww = 0; ww < 4; ++ww) {
            a  += s_red[(ww * 8 + j) * 64 + lane];
            rr += s_red[(ww * 8 + 4 + j) * 64 + lane];
        }
        int e = h * 32 + dg * 4 + j;
        OR[(size_t)r * 512 + e]       = a * inv;
        OR[(size_t)r * 512 + 256 + e] = rr * inv;
    }
}

// ---------------- fused global attention (scores+softmax+PV) ----------------
// Block per (b,h,g). Keys 0..2047 = KVG spatial rows, 2048..2079 = GKVQ glob rows.
__global__ __launch_bounds__(256) void ga_fused_k(
    const float* __restrict__ GKVQ, const float* __restrict__ KVG,
    float* __restrict__ OG)
{
    __shared__ float s_p[ROWS_B];
    __shared__ float s_r[8];
    __shared__ float s_acc[8][32];
    int blk = blockIdx.x, t = threadIdx.x;
    int b = blk >> 8, rem = blk & 255;
    int h = rem >> 5, g = rem & 31;
    int wv = t >> 6;

    float4 qv[8];
    const float* qbase = GKVQ + ((size_t)(b * NG + g)) * 768 + 512 + h * 32;
    #pragma unroll
    for (int i = 0; i < 8; ++i) qv[i] = *(const float4*)(qbase + 4 * i);

    float myS[9];
    float lm = -3.0e38f;
    #pragma unroll
    for (int i = 0; i < 9; ++i) {
        int c = t + (i << 8);
        if (c < ROWS_B) {
            const float* kr = (c < LS)
                ? KVG + ((size_t)(b * LS + c)) * 512 + h * 32
                : GKVQ + ((size_t)(b * NG + (c - LS))) * 768 + h * 32;
            float sc = 0.0f;
            #pragma unroll
            for (int ii = 0; ii < 8; ++ii) sc += dot4(qv[ii], *(const float4*)(kr + 4 * ii));
            sc *= SCALE;
            myS[i] = sc;
            lm = fmaxf(lm, sc);
        }
    }
    #pragma unroll
    for (int m = 32; m >= 1; m >>= 1) lm = fmaxf(lm, __shfl_xor(lm, m));
    if ((t & 63) == 0) s_r[wv] = lm;
    __syncthreads();
    float mx = fmaxf(fmaxf(s_r[0], s_r[1]), fmaxf(s_r[2], s_r[3]));
    float ls = 0.0f;
    #pragma unroll
    for (int i = 0; i < 9; ++i) {
        int c = t + (i << 8);
        if (c < ROWS_B) { float e = __expf(myS[i] - mx); myS[i] = e; ls += e; }
    }
    #pragma unroll
    for (int m = 32; m >= 1; m >>= 1) ls += __shfl_xor(ls, m);
    if ((t & 63) == 0) s_r[4 + wv] = ls;
    #pragma unroll
    for (int i = 0; i < 9; ++i) {
        int c = t + (i << 8);
        if (c < ROWS_B) s_p[c] = myS[i];
    }
    __syncthreads();
    float inv = 1.0f / (s_r[4] + s_r[5] + s_r[6] + s_r[7]);

    // PV: thread (e = t&31, s = t>>5) over key chunk s
    int e = t & 31, s = t >> 5;
    int c0 = s * 260, c1 = c0 + 260;
    float a = 0.0f;
    int cmid = (c1 < LS) ? c1 : LS;
    for (int c = c0; c < cmid; ++c)
        a += s_p[c] * KVG[((size_t)(b * LS + c)) * 512 + 256 + h * 32 + e];
    for (int c = (c0 > LS ? c0 : LS); c < c1; ++c)
        a += s_p[c] * GKVQ[((size_t)(b * NG + (c - LS))) * 768 + 256 + h * 32 + e];
    s_acc[s][e] = a;
    __syncthreads();
    if (t < 32) {
        float o = 0.0f;
        #pragma unroll
        for (int ss = 0; ss < 8; ++ss) o += s_acc[ss][t];
        OG[((size_t)(b * NG + g)) * 256 + h * 32 + t] = o * inv;
    }
}

// ---------------- fused glob tail: og@Wo + res + ln4 + FF + res ----------------
__global__ __launch_bounds__(256) void glob_tail_k(
    const float* __restrict__ OG, const float* __restrict__ latents,
    const float* __restrict__ ga_wo, const float* __restrict__ ga_bo,
    const float* __restrict__ ln4g, const float* __restrict__ ln4b,
    const float* __restrict__ w1, const float* __restrict__ b1,
    const float* __restrict__ w2, const float* __restrict__ b2,
    float* __restrict__ out)
{
    __shared__ float s_og[256];
    __shared__ float s_y[256];
    __shared__ float s_h1[1024];
    __shared__ float red[8];
    int bg = blockIdx.x, t = threadIdx.x;
    int b = bg >> 5;
    size_t row = (size_t)b * ROWS_B + LS + (bg & 31);

    s_og[t] = OG[(size_t)bg * 256 + t];
    __syncthreads();
    float x = 0.0f;
    for (int k = 0; k < 256; ++k) x += s_og[k] * ga_wo[(size_t)k * 256 + t];
    float res = latents[row * 256 + t] + x + ga_bo[t];

    float a = res, b2s = res * res;
    #pragma unroll
    for (int m = 32; m >= 1; m >>= 1) { a += __shfl_xor(a, m); b2s += __shfl_xor(b2s, m); }
    if ((t & 63) == 0) { red[t >> 6] = a; red[4 + (t >> 6)] = b2s; }
    __syncthreads();
    float mean = (red[0] + red[1] + red[2] + red[3]) * (1.0f / 256.0f);
    float var  = (red[4] + red[5] + red[6] + red[7]) * (1.0f / 256.0f) - mean * mean;
    float y = (res - mean) * rsqrtf(var + 1e-5f) * ln4g[t] + ln4b[t];
    s_y[t] = y;
    __syncthreads();

    float4 h1 = *(const float4*)(b1 + t * 4);
    for (int k = 0; k < 256; ++k) {
        float yv = s_y[k];
        float4 wv = *(const float4*)(w1 + (size_t)k * 1024 + t * 4);
        h1.x += yv * wv.x; h1.y += yv * wv.y; h1.z += yv * wv.z; h1.w += yv * wv.w;
    }
    s_h1[t * 4 + 0] = gelu_f(h1.x);
    s_h1[t * 4 + 1] = gelu_f(h1.y);
    s_h1[t * 4 + 2] = gelu_f(h1.z);
    s_h1[t * 4 + 3] = gelu_f(h1.w);
    __syncthreads();

    float o = b2[t];
    for (int j = 0; j < 1024; ++j) o += s_h1[j] * w2[(size_t)j * 256 + t];
    out[row * 256 + t] = res + o;
}

// ---------------- launch ----------------
extern "C" void kernel_launch(void* const* d_in, const int* in_sizes, int n_in,
                              void* d_out, int out_size, void* d_ws, size_t ws_size,
                              hipStream_t stream)
{
    const float* latents = (const float*)d_in[0];
    const int*   idx     = (const int*)d_in[1];
    const float* rpe     = (const float*)d_in[2];
    const float* srpe    = (const float*)d_in[3];
    const float* dist    = (const float*)d_in[4];
    const float* sa_wq   = (const float*)d_in[6];
    const float* sa_wk   = (const float*)d_in[7];
    const float* sa_wv   = (const float*)d_in[8];
    const float* sa_wo   = (const float*)d_in[9];
    const float* sa_bo   = (const float*)d_in[10];
    const float* lsig    = (const float*)d_in[11];
    const float* gbias   = (const float*)d_in[12];
    const float* ln1g    = (const float*)d_in[13];
    const float* ln1b    = (const float*)d_in[14];
    const float* ln2g    = (const float*)d_in[15];
    const float* ln2b    = (const float*)d_in[16];
    const float* sff_w1  = (const float*)d_in[17];
    const float* sff_b1  = (const float*)d_in[18];
    const float* sff_w2  = (const float*)d_in[19];
    const float* sff_b2  = (const float*)d_in[20];
    const float* ga_wq   = (const float*)d_in[21];
    const float* ga_wk   = (const float*)d_in[22];
    const float* ga_wv   = (const float*)d_in[23];
    const float* ga_wo   = (const float*)d_in[24];
    const float* ga_bo   = (const float*)d_in[25];
    const float* ln3g    = (const float*)d_in[27];
    const float* ln3b    = (const float*)d_in[28];
    const float* ln4g    = (const float*)d_in[29];
    const float* ln4b    = (const float*)d_in[30];
    const float* gff_w1  = (const float*)d_in[31];
    const float* gff_b1  = (const float*)d_in[32];
    const float* gff_w2  = (const float*)d_in[33];
    const float* gff_b2  = (const float*)d_in[34];
    float* out = (float*)d_out;

    const size_t SZ = (size_t)4096 * 256;
    float* ws = (float*)d_ws;
    float* X = ws;                                    // [0, 1SZ)
    unsigned short* QKVb = (unsigned short*)(ws + SZ);// [1SZ,3SZ) bf16 [4096][1024]
    unsigned short* H1b  = QKVb;                      // overlays after attn
    float* KVG = ws + SZ;                             // overlays after ff2; [4096][512]
    float* OR_ = ws + 3 * SZ;                         // [3SZ,5SZ) f32 [4096][512]
    unsigned short* wt = (unsigned short*)(ws + 5 * SZ);
    unsigned short* wt_qkvw = wt;                     // [1024][256]
    unsigned short* wt_ff1  = wt + 262144;            // [1024][256]
    unsigned short* wt_ff2  = wt + 524288;            // [256][1024]
    unsigned short* wt_gakv = wt + 786432;            // gak|gav|gaq [768][256]
    unsigned short* wt_wo2  = wt + 983040;            // [256][512]
    float* smalls = ws + 5 * SZ + 558080;
    float* KVGL = smalls;                             // [64][512]
    float* GQ   = KVGL + 32768;                       // [64][256]
    float* GKVQ = GQ + 16384;                         // [64][768]
    float* OG   = GKVQ + 49152;                       // [64][256]

    dim3 blk(256);

    // weight prep
    wspecial_k<<<dim3(512), blk, 0, stream>>>(sa_wq, sa_wk, sa_wv, sa_wo, wt_qkvw, wt_wo2);
    WTab tab;
    tab.e[0] = { sa_wq,  wt_qkvw,           256,  256,   0 };
    tab.e[1] = { sa_wk,  wt_qkvw + 65536,   256,  256,  16 };
    tab.e[2] = { sa_wv,  wt_qkvw + 131072,  256,  256,  32 };
    tab.e[3] = { sff_w1, wt_ff1,            256, 1024,  48 };
    tab.e[4] = { sff_w2, wt_ff2,           1024,  256, 112 };
    tab.e[5] = { ga_wk,  wt_gakv,           256,  256, 176 };
    tab.e[6] = { ga_wv,  wt_gakv + 65536,   256,  256, 192 };
    tab.e[7] = { ga_wq,  wt_gakv + 131072,  256,  256, 208 };
    tab.e[8] = { sa_wq,  wt_qkvw,           256,  256, 1 << 30 };
    wconv_all_k<<<dim3(224), blk, 0, stream>>>(tab);

    // LN1 + LN3
    ln_dual_k<<<dim3(4160), blk, 0, stream>>>(latents, ln1g, ln1b, ln3g, ln3b, X, GQ);

    // QKV+qw projection (bf16 out) and spatial-attn glob K|V (raw latents)
    mgemm_k<0,0,0,0,1><<<dim3(16,64), blk, 0, stream>>>(X, wt_qkvw, nullptr, nullptr, QKVb,
        4096,1024,256,256, 4096,4096,0, 4096,4096,0);
    mgemm_k<0,0,0,0,0><<<dim3(8,1), blk, 0, stream>>>(latents, wt_qkvw + 65536, nullptr, nullptr, KVGL,
        64,512,256,256, 32,ROWS_B,LS, 64,64,0);

    // fused spatial attention -> OR = [O_base | R]
    attn_sp_k<<<dim3(4096), blk, 0, stream>>>(QKVb, KVGL, idx, rpe, srpe, dist, lsig, gbias, OR_);

    // spatial residual: out = latents + OR @ [Wo;Wvo] + bo
    mgemm_k<1,0,1,0,0><<<dim3(4,64), blk, 0, stream>>>(OR_, wt_wo2, sa_bo, latents, out,
        4096,256,512,512, 4096,4096,0, LS,ROWS_B,0);

    // spatial FF
    ln_rows_k<<<dim3(4096), blk, 0, stream>>>(out, ln2g, ln2b, X);
    mgemm_k<1,1,0,0,1><<<dim3(16,64), blk, 0, stream>>>(X, wt_ff1, sff_b1, nullptr, H1b,
        4096,1024,256,256, 4096,4096,0, 4096,4096,0);
    mgemm_k<1,0,1,1,0><<<dim3(4,64), blk, 0, stream>>>(H1b, wt_ff2, sff_b2, out, out,
        4096,256,1024,1024, 4096,4096,0, LS,ROWS_B,0);

    // global attention projections
    mgemm_k<0,0,0,0,0><<<dim3(8,64), blk, 0, stream>>>(out, wt_gakv, nullptr, nullptr, KVG,
        4096,512,256,256, LS,ROWS_B,0, 4096,4096,0);
    mgemm_k<0,0,0,0,0><<<dim3(12,1), blk, 0, stream>>>(GQ, wt_gakv, nullptr, nullptr, GKVQ,
        64,768,256,256, 64,64,0, 64,64,0);

    // fused global attention + glob tail
    ga_fused_k<<<dim3(512), blk, 0, stream>>>(GKVQ, KVG, OG);
    glob_tail_k<<<dim3(64), blk, 0, stream>>>(OG, latents, ga_wo, ga_bo, ln4g, ln4b,
                                              gff_w1, gff_b1, gff_w2, gff_b2, out);
}